// Round 4
// baseline (478.243 us; speedup 1.0000x reference)
//
#include <hip/hip_runtime.h>

#define B_ 2
#define S_ 2048
#define E_ 1024
#define H_ 16
#define D_ 64
#define BS_ (B_*S_)
#define PSTR 76   // flash P-lds stride in u16

typedef unsigned short u16;
typedef __attribute__((ext_vector_type(8))) short short8;
typedef __attribute__((ext_vector_type(4))) float floatx4;
typedef __bf16 bf16x8 __attribute__((ext_vector_type(8)));

__device__ __forceinline__ u16 f2bf(float f) {
    unsigned int u = __builtin_bit_cast(unsigned int, f);
    u += 0x7FFFu + ((u >> 16) & 1u);
    return (u16)(u >> 16);
}
__device__ __forceinline__ float bf2f(u16 h) {
    return __builtin_bit_cast(float, (unsigned int)h << 16);
}
__device__ __forceinline__ floatx4 mfma16(short8 a, short8 b, floatx4 c) {
    return __builtin_amdgcn_mfma_f32_16x16x32_bf16(
        __builtin_bit_cast(bf16x8, a), __builtin_bit_cast(bf16x8, b), c, 0, 0, 0);
}
__device__ __forceinline__ void gload_lds16(const void* g, void* l) {
    __builtin_amdgcn_global_load_lds(
        (const __attribute__((address_space(1))) unsigned int*)g,
        (__attribute__((address_space(3))) unsigned int*)l, 16, 0, 0);
}

// ---------------- prep kernels ----------------

__global__ __launch_bounds__(256) void rope_table_kernel(float* __restrict__ cost,
                                                         float* __restrict__ sint) {
    int idx = blockIdx.x * 256 + threadIdx.x;   // S_*32
    int s = idx >> 5, i = idx & 31;
    float inv = powf(10000.0f, -(float)i / 32.0f);
    float a = (float)s * inv;
    cost[idx] = cosf(a);
    sint[idx] = sinf(a);
}

// x fp32 -> xcat[row][2048] bf16: cols 0..1023 = hi(x), 1024..2047 = lo residual
__global__ __launch_bounds__(256) void convert_x_kernel(const float* __restrict__ X,
                                                        u16* __restrict__ xcat) {
    int i = blockIdx.x * 256 + threadIdx.x;     // BS_*E_/4 float4s
    int row = i >> 8, c4 = (i & 255) * 4;
    float4 v = ((const float4*)X)[i];
    u16 h0 = f2bf(v.x), h1 = f2bf(v.y), h2 = f2bf(v.z), h3 = f2bf(v.w);
    uint2 o;
    o.x = (unsigned)h0 | ((unsigned)h1 << 16);
    o.y = (unsigned)h2 | ((unsigned)h3 << 16);
    *(uint2*)&xcat[(size_t)row * 2048 + c4] = o;
    u16 l0 = f2bf(v.x - bf2f(h0)), l1 = f2bf(v.y - bf2f(h1));
    u16 l2 = f2bf(v.z - bf2f(h2)), l3 = f2bf(v.w - bf2f(h3));
    uint2 ol;
    ol.x = (unsigned)l0 | ((unsigned)l1 << 16);
    ol.y = (unsigned)l2 | ((unsigned)l3 << 16);
    *(uint2*)&xcat[(size_t)row * 2048 + 1024 + c4] = ol;
}

// W [K][N] fp32 -> Wt [N][K] bf16 hi; optional Wres [N][2048] = [lo | hi]
__global__ __launch_bounds__(256) void transpose_w_kernel(const float* __restrict__ W,
                                                          u16* __restrict__ Wt,
                                                          u16* __restrict__ Wres) {
    __shared__ float t[32][33];
    int ntn = E_ / 32;
    int bx = blockIdx.x;
    int tk = (bx / ntn) * 32, tn = (bx % ntn) * 32;
    int tx = threadIdx.x & 31, ty = threadIdx.x >> 5;   // 32 x 8
    for (int i = 0; i < 32; i += 8)
        t[ty + i][tx] = W[(size_t)(tk + ty + i) * E_ + tn + tx];
    __syncthreads();
    for (int i = 0; i < 32; i += 8) {
        float v = t[tx][ty + i];
        u16 hi = f2bf(v);
        Wt[(size_t)(tn + ty + i) * E_ + tk + tx] = hi;
        if (Wres) {
            Wres[(size_t)(tn + ty + i) * 2048 + tk + tx] = f2bf(v - bf2f(hi));
            Wres[(size_t)(tn + ty + i) * 2048 + 1024 + tk + tx] = hi;
        }
    }
}

// ---------------- GEMM core (128x128 tile, global_load_lds staging) ----------------

__device__ __forceinline__ void stage_tile(const u16* __restrict__ src, int row0, int k0,
                                           int stride, u16* lds, int tid) {
    int wv = tid >> 6, ln = tid & 63;
#pragma unroll
    for (int i = 0; i < 4; ++i) {
        int seg = i * 4 + wv;                 // 0..15
        int chunk = seg * 64 + ln;            // 0..1023
        int r = chunk >> 3;
        int c = (chunk & 7) * 8;
        gload_lds16(&src[(size_t)(row0 + r) * stride + k0 + c],
                    (char*)lds + (size_t)seg * 1024);
    }
}

__device__ __forceinline__ void gemm_tile_body(const u16* lA, const u16* lB,
                                               floatx4 (*acc)[4], int lane, int wave) {
    int wm = (wave >> 1) * 64, wn = (wave & 1) * 64;
    int lr = lane & 15, lk = (lane >> 4) * 8;
#pragma unroll
    for (int kk = 0; kk < 64; kk += 32) {
        short8 afr[4], bfr[4];
#pragma unroll
        for (int mi = 0; mi < 4; ++mi)
            afr[mi] = *(const short8*)&lA[(wm + mi * 16 + lr) * 64 + kk + lk];
#pragma unroll
        for (int ni = 0; ni < 4; ++ni)
            bfr[ni] = *(const short8*)&lB[(wn + ni * 16 + lr) * 64 + kk + lk];
        __builtin_amdgcn_s_setprio(1);
#pragma unroll
        for (int mi = 0; mi < 4; ++mi)
#pragma unroll
            for (int ni = 0; ni < 4; ++ni)
                acc[mi][ni] = mfma16(afr[mi], bfr[ni], acc[mi][ni]);
        __builtin_amdgcn_s_setprio(0);
    }
}

__device__ __forceinline__ void gemm_write(float* __restrict__ C, floatx4 (*acc)[4],
                                           int m0, int n0, int N, int lane, int wave) {
    int wm = (wave >> 1) * 64, wn = (wave & 1) * 64;
    int lr = lane & 15, lq = lane >> 4;
#pragma unroll
    for (int mi = 0; mi < 4; ++mi)
#pragma unroll
        for (int ni = 0; ni < 4; ++ni)
#pragma unroll
            for (int r = 0; r < 4; ++r)
                C[(size_t)(m0 + wm + mi * 16 + lq * 4 + r) * N + n0 + wn + ni * 16 + lr]
                    = acc[mi][ni][r];
}

// 4-pass projection GEMM: grid 1024, XCD-swizzled, passes interleaved per XCD.
// pass 0: kres = x_hi@wk_lo + x_lo@wk_hi  (Kd=2048 via concatenated operands)
// pass 1: qf = x_hi@wq ; pass 2: kf = x_hi@wk ; pass 3: vf = x_hi@wv
__global__ __launch_bounds__(256) void proj_gemm_kernel(const u16* __restrict__ xcat,
                                                        const u16* __restrict__ wqt,
                                                        const u16* __restrict__ wkt,
                                                        const u16* __restrict__ wkres,
                                                        const u16* __restrict__ wvt,
                                                        float* __restrict__ qf,
                                                        float* __restrict__ kf,
                                                        float* __restrict__ kres,
                                                        float* __restrict__ vf) {
    __shared__ __align__(16) u16 lA[128 * 64];
    __shared__ __align__(16) u16 lB[128 * 64];
    int bx = blockIdx.x;
    int lbx = (bx & 7) * 128 + (bx >> 3);     // bijective: 1024 % 8 == 0
    int pass = lbx & 3;                       // passes interleaved within each XCD
    int idx = lbx >> 2;                       // 0..255
    int m0 = (idx >> 3) * 128, n0 = (idx & 7) * 128;
    int tid = threadIdx.x, lane = tid & 63, wave = tid >> 6;

    const u16* Bt; int bstride, Kd; float* out;
    if (pass == 0)      { Bt = wkres; bstride = 2048; Kd = 2048; out = kres; }
    else if (pass == 1) { Bt = wqt;   bstride = 1024; Kd = 1024; out = qf; }
    else if (pass == 2) { Bt = wkt;   bstride = 1024; Kd = 1024; out = kf; }
    else                { Bt = wvt;   bstride = 1024; Kd = 1024; out = vf; }

    floatx4 acc[4][4];
#pragma unroll
    for (int i = 0; i < 4; ++i)
#pragma unroll
        for (int j = 0; j < 4; ++j) acc[i][j] = (floatx4){0.f, 0.f, 0.f, 0.f};

    for (int k0 = 0; k0 < Kd; k0 += 64) {
        stage_tile(xcat, m0, k0, 2048, lA, tid);
        stage_tile(Bt, n0, k0, bstride, lB, tid);
        __syncthreads();
        gemm_tile_body(lA, lB, acc, lane, wave);
        __syncthreads();
    }
    gemm_write(out, acc, m0, n0, E_, lane, wave);
}

// plain GEMM (output projection): C[M][N] = A[M][K] @ Bt[N][K]^T
__global__ __launch_bounds__(256) void gemm_bf16_kernel(const u16* __restrict__ A,
                                                        const u16* __restrict__ Bt,
                                                        float* __restrict__ C,
                                                        int M, int N, int Kd) {
    __shared__ __align__(16) u16 lA[128 * 64];
    __shared__ __align__(16) u16 lB[128 * 64];
    int nwg = (M / 128) * (N / 128);
    int bx = blockIdx.x;
    int q = nwg >> 3, rr = nwg & 7, xcd = bx & 7, pos = bx >> 3;
    int lbx = (xcd < rr ? xcd * (q + 1) : rr * (q + 1) + (xcd - rr) * q) + pos;
    int nbn = N / 128;
    int m0 = (lbx / nbn) * 128, n0 = (lbx % nbn) * 128;
    int tid = threadIdx.x, lane = tid & 63, wave = tid >> 6;

    floatx4 acc[4][4];
#pragma unroll
    for (int i = 0; i < 4; ++i)
#pragma unroll
        for (int j = 0; j < 4; ++j) acc[i][j] = (floatx4){0.f, 0.f, 0.f, 0.f};

    for (int k0 = 0; k0 < Kd; k0 += 64) {
        stage_tile(A, m0, k0, Kd, lA, tid);
        stage_tile(Bt, n0, k0, Kd, lB, tid);
        __syncthreads();
        gemm_tile_body(lA, lB, acc, lane, wave);
        __syncthreads();
    }
    gemm_write(C, acc, m0, n0, N, lane, wave);
}

// ---------------- fp32 q for the last token (exact path for top-k) ----------------
__global__ __launch_bounds__(256) void qlast_kernel(const float* __restrict__ x,
                                                    const float* __restrict__ wq,
                                                    float* __restrict__ qlast) {
    __shared__ float red[8][32];
    int bx = blockIdx.x;
    int b = bx >> 5, c0 = (bx & 31) * 32;
    int cl = threadIdx.x & 31, kc = threadIdx.x >> 5;
    const float* xr = &x[((size_t)b * S_ + (S_ - 1)) * E_ + kc * 128];
    const float* wp = &wq[(size_t)(kc * 128) * E_ + c0 + cl];
    float acc = 0.f;
#pragma unroll 4
    for (int e = 0; e < 128; ++e) acc = fmaf(xr[e], wp[(size_t)e * E_], acc);
    red[kc][cl] = acc;
    __syncthreads();
    if (kc == 0) {
        float s = ((red[0][cl] + red[1][cl]) + (red[2][cl] + red[3][cl]))
                + ((red[4][cl] + red[5][cl]) + (red[6][cl] + red[7][cl]));
        qlast[(size_t)b * E_ + c0 + cl] = s;
    }
}

// ---------------- RoPE + rearrange q,k to [b][h][s][d] bf16 ----------------
__global__ __launch_bounds__(256) void rope_qk_kernel(const float* __restrict__ qf,
                                                      const float* __restrict__ kf,
                                                      const float* __restrict__ kres,
                                                      const float* __restrict__ cost,
                                                      const float* __restrict__ sint,
                                                      u16* __restrict__ qb,
                                                      u16* __restrict__ kb) {
    int idx = blockIdx.x * 256 + threadIdx.x;   // B_*S_*H_*32 = 2^21
    int i = idx & 31;
    int h = (idx >> 5) & 15;
    int s = (idx >> 9) & 2047;
    int b = idx >> 20;
    float c = cost[s * 32 + i], sn = sint[s * 32 + i];
    size_t src = ((size_t)b * S_ + s) * E_ + h * 64 + 2 * i;
    float q0 = qf[src], q1 = qf[src + 1];
    float k0 = kf[src] + kres[src];
    float k1 = kf[src + 1] + kres[src + 1];
    size_t dst = (((size_t)(b * H_ + h) * S_) + s) * D_ + 2 * i;
    unsigned qo = (unsigned)f2bf(q0 * c - q1 * sn) | ((unsigned)f2bf(q0 * sn + q1 * c) << 16);
    unsigned ko = (unsigned)f2bf(k0 * c - k1 * sn) | ((unsigned)f2bf(k0 * sn + k1 * c) << 16);
    *(unsigned*)&qb[dst] = qo;
    *(unsigned*)&kb[dst] = ko;
}

// ---------------- V -> vtb [b][h][d][s] bf16 (LDS-tiled transpose) ----------------
__global__ __launch_bounds__(256) void v_transpose_kernel(const float* __restrict__ vf,
                                                          u16* __restrict__ vtb) {
    __shared__ float t[64][65];
    int bx = blockIdx.x;            // b*512 + h*32 + sc
    int sc = bx & 31;
    int h = (bx >> 5) & 15;
    int b = bx >> 9;
    int s0 = sc * 64;
    int tid = threadIdx.x;
    int d = tid & 63, sr = tid >> 6;
    for (int j = 0; j < 64; j += 4)
        t[sr + j][d] = vf[((size_t)b * S_ + s0 + sr + j) * E_ + h * 64 + d];
    __syncthreads();
    int sj = tid & 63, dr = tid >> 6;
    for (int j = 0; j < 64; j += 4)
        vtb[(((size_t)(b * H_ + h)) * D_ + dr + j) * S_ + s0 + sj] = f2bf(t[sj][dr + j]);
}

// ---------------- flash attention: swapped QK^T, software-pipelined K/V ----------------
// __launch_bounds__(256, 2): allow ~256 VGPR so ka/kn/vv prefetches stay live
// (at the default budget the compiler sank the loads to use sites -> exposed latency)
__global__ __launch_bounds__(256, 2) void flash_kernel(const u16* __restrict__ qb,
                                                       const u16* __restrict__ kb,
                                                       const u16* __restrict__ vtb,
                                                       u16* __restrict__ ab) {
    __shared__ __align__(16) u16 ldsP[4][16 * PSTR];   // per-wave P[q=16][k=64]
    int tid = threadIdx.x;
    int lane = tid & 63, wave = tid >> 6;
    int bx = blockIdx.x;
    int xcd = bx & 7, ii = bx >> 3;
    int hid = xcd + 8 * (ii & 3);   // 4 heads per XCD -> K/V L2-resident (2MB/XCD)
    int qc = 31 - (ii >> 2);        // longest q-chunks dispatch first
    int qt0 = qc * 64 + wave * 16;
    const u16* Q = qb + (size_t)hid * S_ * D_;
    const u16* K = kb + (size_t)hid * S_ * D_;
    const u16* V = vtb + (size_t)hid * D_ * S_;
    u16* lp = &ldsP[wave][0];
    int lr = lane & 15, lq = lane >> 4, lk = lq * 8;

    short8 qfr0 = *(const short8*)&Q[(size_t)(qt0 + lr) * D_ + lk];
    short8 qfr1 = *(const short8*)&Q[(size_t)(qt0 + lr) * D_ + 32 + lk];

    floatx4 o0 = {0,0,0,0}, o1 = {0,0,0,0}, o2 = {0,0,0,0}, o3 = {0,0,0,0};
    float m = -1e30f, l = 0.f;      // running stats (base-2 domain) for q = qt0 + lr
    int nend = qt0 + 16;

    // prefetch K tile 0 into registers
    short8 ka0[4], ka1[4];
#pragma unroll
    for (int kt = 0; kt < 4; ++kt) {
        const u16* Kr = &K[(size_t)(kt * 16 + lr) * D_];
        ka0[kt] = *(const short8*)&Kr[lk];
        ka1[kt] = *(const short8*)&Kr[32 + lk];
    }

    for (int n0 = 0; n0 < nend; n0 += 64) {
        int rem = nend - n0;
        int npre = (n0 + 64 < nend) ? n0 + 64 : n0;
        // issue current V loads (consumed at iteration end)
        short8 vv[2][4];
#pragma unroll
        for (int c = 0; c < 2; ++c)
#pragma unroll
            for (int o = 0; o < 4; ++o)
                vv[c][o] = *(const short8*)&V[(size_t)(o * 16 + lr) * S_ + n0 + c * 32 + lk];
        // issue next-iteration K loads
        short8 kn0[4], kn1[4];
#pragma unroll
        for (int kt = 0; kt < 4; ++kt) {
            const u16* Kr = &K[(size_t)(npre + kt * 16 + lr) * D_];
            kn0[kt] = *(const short8*)&Kr[lk];
            kn1[kt] = *(const short8*)&Kr[32 + lk];
        }
        // QK^T swapped: st[kt][r] = S^T[k=n0+kt*16+lq*4+r][q=qt0+lr]
        floatx4 st[4];
#pragma unroll
        for (int kt = 0; kt < 4; ++kt) st[kt] = (floatx4){0.f, 0.f, 0.f, 0.f};
        __builtin_amdgcn_s_setprio(1);
#pragma unroll
        for (int kt = 0; kt < 4; ++kt) {
            st[kt] = mfma16(ka0[kt], qfr0, st[kt]);
            st[kt] = mfma16(ka1[kt], qfr1, st[kt]);
        }
        __builtin_amdgcn_s_setprio(0);
        const float SC = 0.18033688011112042f;   // 0.125 * log2(e)
        float sv[4][4];
        float bmax = -1e30f;
        if (rem >= 80) {                // interior: causal always satisfied
#pragma unroll
            for (int kt = 0; kt < 4; ++kt)
#pragma unroll
                for (int r = 0; r < 4; ++r) {
                    float s = st[kt][r] * SC;
                    sv[kt][r] = s;
                    bmax = fmaxf(bmax, s);
                }
        } else {
#pragma unroll
            for (int kt = 0; kt < 4; ++kt)
#pragma unroll
                for (int r = 0; r < 4; ++r) {
                    int k = n0 + kt * 16 + lq * 4 + r;
                    float s = (k <= qt0 + lr) ? st[kt][r] * SC : -1e30f;
                    sv[kt][r] = s;
                    bmax = fmaxf(bmax, s);
                }
        }
        bmax = fmaxf(bmax, __shfl_xor(bmax, 16));
        bmax = fmaxf(bmax, __shfl_xor(bmax, 32));
        float mn = fmaxf(m, bmax);
        float alpha = __builtin_amdgcn_exp2f(m - mn);
        m = mn;
        float ps = 0.f;
#pragma unroll
        for (int kt = 0; kt < 4; ++kt) {
            float p0 = __builtin_amdgcn_exp2f(sv[kt][0] - mn);
            float p1 = __builtin_amdgcn_exp2f(sv[kt][1] - mn);
            float p2 = __builtin_amdgcn_exp2f(sv[kt][2] - mn);
            float p3 = __builtin_amdgcn_exp2f(sv[kt][3] - mn);
            ps += (p0 + p1) + (p2 + p3);
            unsigned wlo, whi;
            asm("v_cvt_pk_bf16_f32 %0, %1, %2" : "=v"(wlo) : "v"(p0), "v"(p1));
            asm("v_cvt_pk_bf16_f32 %0, %1, %2" : "=v"(whi) : "v"(p2), "v"(p3));
            *(uint2*)&lp[lr * PSTR + kt * 16 + lq * 4] = (uint2){wlo, whi};
        }
        ps += __shfl_xor(ps, 16);
        ps += __shfl_xor(ps, 32);
        l = l * alpha + ps;
        float af[4];
#pragma unroll
        for (int r = 0; r < 4; ++r) af[r] = __shfl(alpha, lq * 4 + r);
#pragma unroll
        for (int r = 0; r < 4; ++r) {
            o0[r] *= af[r]; o1[r] *= af[r]; o2[r] *= af[r]; o3[r] *= af[r];
        }
        asm volatile("s_waitcnt lgkmcnt(0)" ::: "memory");
        // PV: masked P entries are exactly 0 -> unconditional both halves
        __builtin_amdgcn_s_setprio(1);
#pragma unroll
        for (int c = 0; c < 2; ++c) {
            uint2 plo = *(const uint2*)&lp[lr * PSTR + c * 32 + lk];
            uint2 phi = *(const uint2*)&lp[lr * PSTR + c * 32 + lk + 4];
            short8 pfr = __builtin_bit_cast(short8, (uint4){plo.x, plo.y, phi.x, phi.y});
            o0 = mfma16(pfr, vv[c][0], o0);
            o1 = mfma16(pfr, vv[c][1], o1);
            o2 = mfma16(pfr, vv[c][2], o2);
            o3 = mfma16(pfr, vv[c][3], o3);
        }
        __builtin_amdgcn_s_setprio(0);
#pragma unroll
        for (int kt = 0; kt < 4; ++kt) { ka0[kt] = kn0[kt]; ka1[kt] = kn1[kt]; }
    }
    float li[4];
#pragma unroll
    for (int r = 0; r < 4; ++r) li[r] = 1.0f / __shfl(l, lq * 4 + r);
    int b = hid >> 4, h = hid & 15;
    size_t orow_base = ((size_t)b * S_ + qt0 + lq * 4) * E_ + h * D_;
#pragma unroll
    for (int r = 0; r < 4; ++r) {
        size_t rb = orow_base + (size_t)r * E_;
        ab[rb + 0  + lr] = f2bf(o0[r] * li[r]);
        ab[rb + 16 + lr] = f2bf(o1[r] * li[r]);
        ab[rb + 32 + lr] = f2bf(o2[r] * li[r]);
        ab[rb + 48 + lr] = f2bf(o3[r] * li[r]);
    }
}

// ---------------- top-8 tiles from last-row logits (fp32 path) ----------------
__global__ __launch_bounds__(256) void topk_kernel(const float* __restrict__ qlast,
                                                   const float* __restrict__ kf,
                                                   const float* __restrict__ kres,
                                                   const float* __restrict__ cost,
                                                   const float* __restrict__ sint,
                                                   float* __restrict__ oidx) {
    __shared__ float qr[64];
    __shared__ float lmax[256];
    __shared__ float tmax[128];
    int bx = blockIdx.x;            // b*16 + h
    int h = bx & 15, b = bx >> 4;
    int tid = threadIdx.x;
    if (tid < 32) {
        float c = cost[2047 * 32 + tid], sn = sint[2047 * 32 + tid];
        float q0 = qlast[(size_t)b * E_ + h * 64 + 2 * tid];
        float q1 = qlast[(size_t)b * E_ + h * 64 + 2 * tid + 1];
        qr[2 * tid]     = q0 * c - q1 * sn;
        qr[2 * tid + 1] = q0 * sn + q1 * c;
    }
    __syncthreads();
    float best = -1e30f;
    for (int j = 0; j < 8; ++j) {
        int s = tid * 8 + j;
        size_t kbase = ((size_t)b * S_ + s) * E_ + h * 64;
        const float* kr  = &kf[kbase];
        const float* krr = &kres[kbase];
        float acc = 0.f;
#pragma unroll
        for (int i = 0; i < 32; ++i) {
            float c = cost[s * 32 + i], sn = sint[s * 32 + i];
            float k0 = kr[2 * i] + krr[2 * i];
            float k1 = kr[2 * i + 1] + krr[2 * i + 1];
            acc += qr[2 * i] * (k0 * c - k1 * sn) + qr[2 * i + 1] * (k0 * sn + k1 * c);
        }
        best = fmaxf(best, acc);
    }
    lmax[tid] = best;
    __syncthreads();
    if (tid < 128) tmax[tid] = fmaxf(lmax[2 * tid], lmax[2 * tid + 1]);
    __syncthreads();
    if (tid < 64) {                  // wave-parallel top-8 with lowest-index tiebreak
        float v0 = tmax[tid], v1 = tmax[tid + 64];
        float va, vb; int ia, ib;
        if (v1 > v0) { va = v1; ia = tid + 64; vb = v0; ib = tid; }
        else         { va = v0; ia = tid;      vb = v1; ib = tid + 64; }
        float cv = va; int ci = ia; int used = 0;
        for (int t = 0; t < 8; ++t) {
            float bv = cv; int bi = ci;
#pragma unroll
            for (int mk = 1; mk < 64; mk <<= 1) {
                float ov = __shfl_xor(bv, mk);
                int oi = __shfl_xor(bi, mk);
                if (ov > bv || (ov == bv && oi < bi)) { bv = ov; bi = oi; }
            }
            if (tid == 0) oidx[bx * 8 + t] = (float)bi;
            if (ci == bi) {
                if (used == 0) { cv = vb; ci = ib; used = 1; }
                else           { cv = -3e30f; ci = 1 << 20; }
            }
        }
    }
}

// ---------------- launch ----------------
extern "C" void kernel_launch(void* const* d_in, const int* in_sizes, int n_in,
                              void* d_out, int out_size, void* d_ws, size_t ws_size,
                              hipStream_t stream) {
    (void)in_sizes; (void)n_in; (void)out_size; (void)ws_size;
    const float* x  = (const float*)d_in[0];
    const float* wq = (const float*)d_in[1];
    const float* wk = (const float*)d_in[2];
    const float* wv = (const float*)d_in[3];
    const float* wo = (const float*)d_in[4];
    float* out = (float*)d_out;

    char* wsp = (char*)d_ws;
    size_t off = 0;
    auto nxt = [&](size_t bytes) {
        char* p = wsp + off;
        off = (off + bytes + 255) & ~(size_t)255;
        return p;
    };
    u16* xcat  = (u16*)nxt((size_t)BS_ * 2048 * 2);
    u16* wqt   = (u16*)nxt((size_t)E_ * E_ * 2);
    u16* wkt   = (u16*)nxt((size_t)E_ * E_ * 2);
    u16* wkres = (u16*)nxt((size_t)E_ * 2048 * 2);
    u16* wvt   = (u16*)nxt((size_t)E_ * E_ * 2);
    u16* wot   = (u16*)nxt((size_t)E_ * E_ * 2);
    float* qf  = (float*)nxt((size_t)BS_ * E_ * 4);
    float* kf  = (float*)nxt((size_t)BS_ * E_ * 4);
    float* kres = (float*)nxt((size_t)BS_ * E_ * 4);
    float* vf  = (float*)nxt((size_t)BS_ * E_ * 4);
    float* cost = (float*)nxt((size_t)S_ * 32 * 4);
    float* sint = (float*)nxt((size_t)S_ * 32 * 4);
    u16* qb    = (u16*)nxt((size_t)B_ * H_ * S_ * D_ * 2);
    u16* kb    = (u16*)nxt((size_t)B_ * H_ * S_ * D_ * 2);
    u16* vtb   = (u16*)nxt((size_t)B_ * H_ * S_ * D_ * 2);
    u16* ab    = (u16*)nxt((size_t)BS_ * E_ * 2);
    float* qlast = (float*)nxt((size_t)B_ * E_ * 4);

    // prep
    hipLaunchKernelGGL(rope_table_kernel, dim3(S_ * 32 / 256), dim3(256), 0, stream, cost, sint);
    hipLaunchKernelGGL(convert_x_kernel, dim3(BS_ * E_ / 4 / 256), dim3(256), 0, stream, x, xcat);
    hipLaunchKernelGGL(transpose_w_kernel, dim3(1024), dim3(256), 0, stream, wq, wqt, (u16*)nullptr);
    hipLaunchKernelGGL(transpose_w_kernel, dim3(1024), dim3(256), 0, stream, wk, wkt, wkres);
    hipLaunchKernelGGL(transpose_w_kernel, dim3(1024), dim3(256), 0, stream, wv, wvt, (u16*)nullptr);
    hipLaunchKernelGGL(transpose_w_kernel, dim3(1024), dim3(256), 0, stream, wo, wot, (u16*)nullptr);

    // 4-pass projections (K correction fused into one Kd=2048 pass)
    hipLaunchKernelGGL(proj_gemm_kernel, dim3(1024), dim3(256), 0, stream,
                       xcat, wqt, wkt, wkres, wvt, qf, kf, kres, vf);
    hipLaunchKernelGGL(qlast_kernel, dim3(64), dim3(256), 0, stream, x, wq, qlast);

    // rearrange
    hipLaunchKernelGGL(rope_qk_kernel, dim3(B_ * S_ * H_ * 32 / 256), dim3(256), 0, stream,
                       qf, kf, kres, cost, sint, qb, kb);
    hipLaunchKernelGGL(v_transpose_kernel, dim3(B_ * H_ * (S_ / 64)), dim3(256), 0, stream, vf, vtb);

    // attention + top-k
    hipLaunchKernelGGL(flash_kernel, dim3(B_ * H_ * (S_ / 64)), dim3(256), 0, stream, qb, kb, vtb, ab);
    hipLaunchKernelGGL(topk_kernel, dim3(B_ * H_), dim3(256), 0, stream,
                       qlast, kf, kres, cost, sint, out + (size_t)BS_ * E_);

    // output projection
    hipLaunchKernelGGL(gemm_bf16_kernel, dim3(256), dim3(256), 0, stream, ab, wot, out,
                       BS_, E_, E_);
}

// Round 5
// 387.110 us; speedup vs baseline: 1.2354x; 1.2354x over previous
//
#include <hip/hip_runtime.h>

#define B_ 2
#define S_ 2048
#define E_ 1024
#define H_ 16
#define D_ 64
#define BS_ (B_*S_)
#define PSTR 76   // flash P-lds stride in u16

typedef unsigned short u16;
typedef __attribute__((ext_vector_type(8))) short short8;
typedef __attribute__((ext_vector_type(4))) float floatx4;
typedef __bf16 bf16x8 __attribute__((ext_vector_type(8)));

__device__ __forceinline__ u16 f2bf(float f) {
    unsigned int u = __builtin_bit_cast(unsigned int, f);
    u += 0x7FFFu + ((u >> 16) & 1u);
    return (u16)(u >> 16);
}
__device__ __forceinline__ float bf2f(u16 h) {
    return __builtin_bit_cast(float, (unsigned int)h << 16);
}
__device__ __forceinline__ floatx4 mfma16(short8 a, short8 b, floatx4 c) {
    return __builtin_amdgcn_mfma_f32_16x16x32_bf16(
        __builtin_bit_cast(bf16x8, a), __builtin_bit_cast(bf16x8, b), c, 0, 0, 0);
}
__device__ __forceinline__ void gload_lds16(const void* g, void* l) {
    __builtin_amdgcn_global_load_lds(
        (const __attribute__((address_space(1))) unsigned int*)g,
        (__attribute__((address_space(3))) unsigned int*)l, 16, 0, 0);
}

// ---------------- prep kernels ----------------

__global__ __launch_bounds__(256) void rope_table_kernel(float* __restrict__ cost,
                                                         float* __restrict__ sint) {
    int idx = blockIdx.x * 256 + threadIdx.x;   // S_*32
    int s = idx >> 5, i = idx & 31;
    float inv = powf(10000.0f, -(float)i / 32.0f);
    float a = (float)s * inv;
    cost[idx] = cosf(a);
    sint[idx] = sinf(a);
}

// x fp32 -> xcat[row][2048] bf16: cols 0..1023 = hi(x), 1024..2047 = lo residual
__global__ __launch_bounds__(256) void convert_x_kernel(const float* __restrict__ X,
                                                        u16* __restrict__ xcat) {
    int i = blockIdx.x * 256 + threadIdx.x;     // BS_*E_/4 float4s
    int row = i >> 8, c4 = (i & 255) * 4;
    float4 v = ((const float4*)X)[i];
    u16 h0 = f2bf(v.x), h1 = f2bf(v.y), h2 = f2bf(v.z), h3 = f2bf(v.w);
    uint2 o;
    o.x = (unsigned)h0 | ((unsigned)h1 << 16);
    o.y = (unsigned)h2 | ((unsigned)h3 << 16);
    *(uint2*)&xcat[(size_t)row * 2048 + c4] = o;
    u16 l0 = f2bf(v.x - bf2f(h0)), l1 = f2bf(v.y - bf2f(h1));
    u16 l2 = f2bf(v.z - bf2f(h2)), l3 = f2bf(v.w - bf2f(h3));
    uint2 ol;
    ol.x = (unsigned)l0 | ((unsigned)l1 << 16);
    ol.y = (unsigned)l2 | ((unsigned)l3 << 16);
    *(uint2*)&xcat[(size_t)row * 2048 + 1024 + c4] = ol;
}

// W [K][N] fp32 -> Wt [N][K] bf16 hi; optional Wres [N][2048] = [lo | hi]
__global__ __launch_bounds__(256) void transpose_w_kernel(const float* __restrict__ W,
                                                          u16* __restrict__ Wt,
                                                          u16* __restrict__ Wres) {
    __shared__ float t[32][33];
    int ntn = E_ / 32;
    int bx = blockIdx.x;
    int tk = (bx / ntn) * 32, tn = (bx % ntn) * 32;
    int tx = threadIdx.x & 31, ty = threadIdx.x >> 5;   // 32 x 8
    for (int i = 0; i < 32; i += 8)
        t[ty + i][tx] = W[(size_t)(tk + ty + i) * E_ + tn + tx];
    __syncthreads();
    for (int i = 0; i < 32; i += 8) {
        float v = t[tx][ty + i];
        u16 hi = f2bf(v);
        Wt[(size_t)(tn + ty + i) * E_ + tk + tx] = hi;
        if (Wres) {
            Wres[(size_t)(tn + ty + i) * 2048 + tk + tx] = f2bf(v - bf2f(hi));
            Wres[(size_t)(tn + ty + i) * 2048 + 1024 + tk + tx] = hi;
        }
    }
}

// ---------------- GEMM core (128x128 tile, global_load_lds staging) ----------------

__device__ __forceinline__ void stage_tile(const u16* __restrict__ src, int row0, int k0,
                                           int stride, u16* lds, int tid) {
    int wv = tid >> 6, ln = tid & 63;
#pragma unroll
    for (int i = 0; i < 4; ++i) {
        int seg = i * 4 + wv;                 // 0..15
        int chunk = seg * 64 + ln;            // 0..1023
        int r = chunk >> 3;
        int c = (chunk & 7) * 8;
        gload_lds16(&src[(size_t)(row0 + r) * stride + k0 + c],
                    (char*)lds + (size_t)seg * 1024);
    }
}

__device__ __forceinline__ void gemm_tile_body(const u16* lA, const u16* lB,
                                               floatx4 (*acc)[4], int lane, int wave) {
    int wm = (wave >> 1) * 64, wn = (wave & 1) * 64;
    int lr = lane & 15, lk = (lane >> 4) * 8;
#pragma unroll
    for (int kk = 0; kk < 64; kk += 32) {
        short8 afr[4], bfr[4];
#pragma unroll
        for (int mi = 0; mi < 4; ++mi)
            afr[mi] = *(const short8*)&lA[(wm + mi * 16 + lr) * 64 + kk + lk];
#pragma unroll
        for (int ni = 0; ni < 4; ++ni)
            bfr[ni] = *(const short8*)&lB[(wn + ni * 16 + lr) * 64 + kk + lk];
        __builtin_amdgcn_s_setprio(1);
#pragma unroll
        for (int mi = 0; mi < 4; ++mi)
#pragma unroll
            for (int ni = 0; ni < 4; ++ni)
                acc[mi][ni] = mfma16(afr[mi], bfr[ni], acc[mi][ni]);
        __builtin_amdgcn_s_setprio(0);
    }
}

__device__ __forceinline__ void gemm_write(float* __restrict__ C, floatx4 (*acc)[4],
                                           int m0, int n0, int N, int lane, int wave) {
    int wm = (wave >> 1) * 64, wn = (wave & 1) * 64;
    int lr = lane & 15, lq = lane >> 4;
#pragma unroll
    for (int mi = 0; mi < 4; ++mi)
#pragma unroll
        for (int ni = 0; ni < 4; ++ni)
#pragma unroll
            for (int r = 0; r < 4; ++r)
                C[(size_t)(m0 + wm + mi * 16 + lq * 4 + r) * N + n0 + wn + ni * 16 + lr]
                    = acc[mi][ni][r];
}

// 4-pass projection GEMM: grid 1024, XCD-swizzled, passes interleaved per XCD.
__global__ __launch_bounds__(256) void proj_gemm_kernel(const u16* __restrict__ xcat,
                                                        const u16* __restrict__ wqt,
                                                        const u16* __restrict__ wkt,
                                                        const u16* __restrict__ wkres,
                                                        const u16* __restrict__ wvt,
                                                        float* __restrict__ qf,
                                                        float* __restrict__ kf,
                                                        float* __restrict__ kres,
                                                        float* __restrict__ vf) {
    __shared__ __align__(16) u16 lA[128 * 64];
    __shared__ __align__(16) u16 lB[128 * 64];
    int bx = blockIdx.x;
    int lbx = (bx & 7) * 128 + (bx >> 3);     // bijective: 1024 % 8 == 0
    int pass = lbx & 3;                       // passes interleaved within each XCD
    int idx = lbx >> 2;                       // 0..255
    int m0 = (idx >> 3) * 128, n0 = (idx & 7) * 128;
    int tid = threadIdx.x, lane = tid & 63, wave = tid >> 6;

    const u16* Bt; int bstride, Kd; float* out;
    if (pass == 0)      { Bt = wkres; bstride = 2048; Kd = 2048; out = kres; }
    else if (pass == 1) { Bt = wqt;   bstride = 1024; Kd = 1024; out = qf; }
    else if (pass == 2) { Bt = wkt;   bstride = 1024; Kd = 1024; out = kf; }
    else                { Bt = wvt;   bstride = 1024; Kd = 1024; out = vf; }

    floatx4 acc[4][4];
#pragma unroll
    for (int i = 0; i < 4; ++i)
#pragma unroll
        for (int j = 0; j < 4; ++j) acc[i][j] = (floatx4){0.f, 0.f, 0.f, 0.f};

    for (int k0 = 0; k0 < Kd; k0 += 64) {
        stage_tile(xcat, m0, k0, 2048, lA, tid);
        stage_tile(Bt, n0, k0, bstride, lB, tid);
        __syncthreads();
        gemm_tile_body(lA, lB, acc, lane, wave);
        __syncthreads();
    }
    gemm_write(out, acc, m0, n0, E_, lane, wave);
}

// plain GEMM (output projection): C[M][N] = A[M][K] @ Bt[N][K]^T
__global__ __launch_bounds__(256) void gemm_bf16_kernel(const u16* __restrict__ A,
                                                        const u16* __restrict__ Bt,
                                                        float* __restrict__ C,
                                                        int M, int N, int Kd) {
    __shared__ __align__(16) u16 lA[128 * 64];
    __shared__ __align__(16) u16 lB[128 * 64];
    int nwg = (M / 128) * (N / 128);
    int bx = blockIdx.x;
    int q = nwg >> 3, rr = nwg & 7, xcd = bx & 7, pos = bx >> 3;
    int lbx = (xcd < rr ? xcd * (q + 1) : rr * (q + 1) + (xcd - rr) * q) + pos;
    int nbn = N / 128;
    int m0 = (lbx / nbn) * 128, n0 = (lbx % nbn) * 128;
    int tid = threadIdx.x, lane = tid & 63, wave = tid >> 6;

    floatx4 acc[4][4];
#pragma unroll
    for (int i = 0; i < 4; ++i)
#pragma unroll
        for (int j = 0; j < 4; ++j) acc[i][j] = (floatx4){0.f, 0.f, 0.f, 0.f};

    for (int k0 = 0; k0 < Kd; k0 += 64) {
        stage_tile(A, m0, k0, Kd, lA, tid);
        stage_tile(Bt, n0, k0, Kd, lB, tid);
        __syncthreads();
        gemm_tile_body(lA, lB, acc, lane, wave);
        __syncthreads();
    }
    gemm_write(C, acc, m0, n0, N, lane, wave);
}

// ---------------- fp32 q for the last token (exact path for top-k) ----------------
__global__ __launch_bounds__(256) void qlast_kernel(const float* __restrict__ x,
                                                    const float* __restrict__ wq,
                                                    float* __restrict__ qlast) {
    __shared__ float red[8][32];
    int bx = blockIdx.x;
    int b = bx >> 5, c0 = (bx & 31) * 32;
    int cl = threadIdx.x & 31, kc = threadIdx.x >> 5;
    const float* xr = &x[((size_t)b * S_ + (S_ - 1)) * E_ + kc * 128];
    const float* wp = &wq[(size_t)(kc * 128) * E_ + c0 + cl];
    float acc = 0.f;
#pragma unroll 4
    for (int e = 0; e < 128; ++e) acc = fmaf(xr[e], wp[(size_t)e * E_], acc);
    red[kc][cl] = acc;
    __syncthreads();
    if (kc == 0) {
        float s = ((red[0][cl] + red[1][cl]) + (red[2][cl] + red[3][cl]))
                + ((red[4][cl] + red[5][cl]) + (red[6][cl] + red[7][cl]));
        qlast[(size_t)b * E_ + c0 + cl] = s;
    }
}

// ---------------- RoPE + rearrange q,k to [b][h][s][d] bf16 ----------------
__global__ __launch_bounds__(256) void rope_qk_kernel(const float* __restrict__ qf,
                                                      const float* __restrict__ kf,
                                                      const float* __restrict__ kres,
                                                      const float* __restrict__ cost,
                                                      const float* __restrict__ sint,
                                                      u16* __restrict__ qb,
                                                      u16* __restrict__ kb) {
    int idx = blockIdx.x * 256 + threadIdx.x;   // B_*S_*H_*32 = 2^21
    int i = idx & 31;
    int h = (idx >> 5) & 15;
    int s = (idx >> 9) & 2047;
    int b = idx >> 20;
    float c = cost[s * 32 + i], sn = sint[s * 32 + i];
    size_t src = ((size_t)b * S_ + s) * E_ + h * 64 + 2 * i;
    float q0 = qf[src], q1 = qf[src + 1];
    float k0 = kf[src] + kres[src];
    float k1 = kf[src + 1] + kres[src + 1];
    size_t dst = (((size_t)(b * H_ + h) * S_) + s) * D_ + 2 * i;
    unsigned qo = (unsigned)f2bf(q0 * c - q1 * sn) | ((unsigned)f2bf(q0 * sn + q1 * c) << 16);
    unsigned ko = (unsigned)f2bf(k0 * c - k1 * sn) | ((unsigned)f2bf(k0 * sn + k1 * c) << 16);
    *(unsigned*)&qb[dst] = qo;
    *(unsigned*)&kb[dst] = ko;
}

// ---------------- V -> vtb [b][h][d][s] bf16 (LDS-tiled transpose) ----------------
__global__ __launch_bounds__(256) void v_transpose_kernel(const float* __restrict__ vf,
                                                          u16* __restrict__ vtb) {
    __shared__ float t[64][65];
    int bx = blockIdx.x;            // b*512 + h*32 + sc
    int sc = bx & 31;
    int h = (bx >> 5) & 15;
    int b = bx >> 9;
    int s0 = sc * 64;
    int tid = threadIdx.x;
    int d = tid & 63, sr = tid >> 6;
    for (int j = 0; j < 64; j += 4)
        t[sr + j][d] = vf[((size_t)b * S_ + s0 + sr + j) * E_ + h * 64 + d];
    __syncthreads();
    int sj = tid & 63, dr = tid >> 6;
    for (int j = 0; j < 64; j += 4)
        vtb[(((size_t)(b * H_ + h)) * D_ + dr + j) * S_ + s0 + sj] = f2bf(t[sj][dr + j]);
}

// ---------------- flash attention v3: LDS-DMA staged K/V, fragment-major segs ----------------
// Per block: 64 q rows (4 waves x 16). K/V tiles (64x64) double-buffered in LDS via
// global_load_lds; LDS layout is fragment-major (seg = one MFMA fragment in lane order),
// achieved by per-lane swizzled GLOBAL source addresses + linear LDS dest (rule #21).
// Reads are ds_read_b128 at lane*16B: conflict-free, zero repack.
__device__ __forceinline__ void stage_kv(const u16* __restrict__ K, const u16* __restrict__ V,
                                         int n0, u16* kbuf, u16* vbuf, int wave, int lane) {
    int lr = lane & 15, lq = lane >> 4;
    if (wave < 2) {
#pragma unroll
        for (int i = 0; i < 4; ++i) {
            int sk = wave * 4 + i;            // seg = kt*2 + kh
            int kt = sk >> 1, kh = (sk & 1) * 32;
            gload_lds16(&K[(size_t)(n0 + kt * 16 + lr) * D_ + kh + lq * 8],
                        kbuf + sk * 512);
        }
    } else {
#pragma unroll
        for (int i = 0; i < 4; ++i) {
            int sv = (wave - 2) * 4 + i;      // seg = c*4 + o
            int c = sv >> 2, o = sv & 3;
            gload_lds16(&V[(size_t)(o * 16 + lr) * S_ + n0 + c * 32 + lq * 8],
                        vbuf + sv * 512);
        }
    }
}

__global__ __launch_bounds__(256) void flash_kernel(const u16* __restrict__ qb,
                                                    const u16* __restrict__ kb,
                                                    const u16* __restrict__ vtb,
                                                    u16* __restrict__ ab) {
    __shared__ __align__(16) u16 kls[2][8 * 512];      // 8KB per buffer
    __shared__ __align__(16) u16 vls[2][8 * 512];      // 8KB per buffer
    __shared__ __align__(16) u16 ldsP[4][16 * PSTR];   // per-wave P[q=16][k=64]
    int tid = threadIdx.x;
    int lane = tid & 63, wave = tid >> 6;
    int bx = blockIdx.x;
    int xcd = bx & 7, ii = bx >> 3;
    int hid = xcd + 8 * (ii & 3);   // 4 heads per XCD -> K/V L2-resident
    int qc = 31 - (ii >> 2);        // longest q-chunks dispatch first
    int qt0 = qc * 64 + wave * 16;
    const u16* Q = qb + (size_t)hid * S_ * D_;
    const u16* K = kb + (size_t)hid * S_ * D_;
    const u16* V = vtb + (size_t)hid * D_ * S_;
    u16* lp = &ldsP[wave][0];
    int lr = lane & 15, lq = lane >> 4, lk = lq * 8;

    short8 qfr0 = *(const short8*)&Q[(size_t)(qt0 + lr) * D_ + lk];
    short8 qfr1 = *(const short8*)&Q[(size_t)(qt0 + lr) * D_ + 32 + lk];

    floatx4 o0 = {0,0,0,0}, o1 = {0,0,0,0}, o2 = {0,0,0,0}, o3 = {0,0,0,0};
    float m = -1e30f, l = 0.f;      // running stats (base-2 domain) for q = qt0 + lr

    // prologue: stage tile 0
    stage_kv(K, V, 0, kls[0], vls[0], wave, lane);
    asm volatile("s_waitcnt vmcnt(0)" ::: "memory");
    __syncthreads();

    for (int it = 0; it <= qc; ++it) {
        int n0 = it * 64;
        int buf = it & 1;
        const u16* kbuf = kls[buf];
        const u16* vbuf = vls[buf];
        if (it < qc)
            stage_kv(K, V, n0 + 64, kls[buf ^ 1], vls[buf ^ 1], wave, lane);

        // --- QK^T (swapped): frag reads are linear lane*16B -> conflict-free
        short8 ka0[4], ka1[4];
#pragma unroll
        for (int kt = 0; kt < 4; ++kt) {
            ka0[kt] = *(const short8*)&kbuf[(kt * 2 + 0) * 512 + lane * 8];
            ka1[kt] = *(const short8*)&kbuf[(kt * 2 + 1) * 512 + lane * 8];
        }
        floatx4 st[4];
#pragma unroll
        for (int kt = 0; kt < 4; ++kt) st[kt] = (floatx4){0.f, 0.f, 0.f, 0.f};
        __builtin_amdgcn_s_setprio(1);
#pragma unroll
        for (int kt = 0; kt < 4; ++kt) {
            st[kt] = mfma16(ka0[kt], qfr0, st[kt]);
            st[kt] = mfma16(ka1[kt], qfr1, st[kt]);
        }
        __builtin_amdgcn_s_setprio(0);

        const float SC = 0.18033688011112042f;   // 0.125 * log2(e)
        int rem = qt0 + 16 - n0;
        float sv[4][4];
        float bmax = -1e30f;
        if (rem >= 80) {                // interior: causal always satisfied
#pragma unroll
            for (int kt = 0; kt < 4; ++kt)
#pragma unroll
                for (int r = 0; r < 4; ++r) {
                    float s = st[kt][r] * SC;
                    sv[kt][r] = s;
                    bmax = fmaxf(bmax, s);
                }
        } else {
#pragma unroll
            for (int kt = 0; kt < 4; ++kt)
#pragma unroll
                for (int r = 0; r < 4; ++r) {
                    int k = n0 + kt * 16 + lq * 4 + r;
                    float s = (k <= qt0 + lr) ? st[kt][r] * SC : -1e30f;
                    sv[kt][r] = s;
                    bmax = fmaxf(bmax, s);
                }
        }
        bmax = fmaxf(bmax, __shfl_xor(bmax, 16));
        bmax = fmaxf(bmax, __shfl_xor(bmax, 32));
        // defer-max (T13): skip rescale when max grew by < 8 (base-2)
        if (!__all(bmax <= m + 8.0f)) {
            float mn = fmaxf(m, bmax);
            float alpha = __builtin_amdgcn_exp2f(m - mn);
            m = mn;
            l *= alpha;
            float af[4];
#pragma unroll
            for (int r = 0; r < 4; ++r) af[r] = __shfl(alpha, lq * 4 + r);
#pragma unroll
            for (int r = 0; r < 4; ++r) {
                o0[r] *= af[r]; o1[r] *= af[r]; o2[r] *= af[r]; o3[r] *= af[r];
            }
        }
        float ps = 0.f;
#pragma unroll
        for (int kt = 0; kt < 4; ++kt) {
            float p0 = __builtin_amdgcn_exp2f(sv[kt][0] - m);
            float p1 = __builtin_amdgcn_exp2f(sv[kt][1] - m);
            float p2 = __builtin_amdgcn_exp2f(sv[kt][2] - m);
            float p3 = __builtin_amdgcn_exp2f(sv[kt][3] - m);
            ps += (p0 + p1) + (p2 + p3);
            unsigned wlo, whi;
            asm("v_cvt_pk_bf16_f32 %0, %1, %2" : "=v"(wlo) : "v"(p0), "v"(p1));
            asm("v_cvt_pk_bf16_f32 %0, %1, %2" : "=v"(whi) : "v"(p2), "v"(p3));
            *(uint2*)&lp[lr * PSTR + kt * 16 + lq * 4] = (uint2){wlo, whi};
        }
        ps += __shfl_xor(ps, 16);
        ps += __shfl_xor(ps, 32);
        l += ps;

        // --- V frags (linear lane*16B reads)
        short8 vv[2][4];
#pragma unroll
        for (int c = 0; c < 2; ++c)
#pragma unroll
            for (int o = 0; o < 4; ++o)
                vv[c][o] = *(const short8*)&vbuf[(c * 4 + o) * 512 + lane * 8];
        asm volatile("s_waitcnt lgkmcnt(0)" ::: "memory");
        // --- PV: masked P entries are exactly 0 -> unconditional both halves
        __builtin_amdgcn_s_setprio(1);
#pragma unroll
        for (int c = 0; c < 2; ++c) {
            uint2 plo = *(const uint2*)&lp[lr * PSTR + c * 32 + lk];
            uint2 phi = *(const uint2*)&lp[lr * PSTR + c * 32 + lk + 4];
            short8 pfr = __builtin_bit_cast(short8, (uint4){plo.x, plo.y, phi.x, phi.y});
            o0 = mfma16(pfr, vv[c][0], o0);
            o1 = mfma16(pfr, vv[c][1], o1);
            o2 = mfma16(pfr, vv[c][2], o2);
            o3 = mfma16(pfr, vv[c][3], o3);
        }
        __builtin_amdgcn_s_setprio(0);

        if (it < qc) {
            asm volatile("s_waitcnt vmcnt(0)" ::: "memory");
            __syncthreads();
        }
    }
    float li[4];
#pragma unroll
    for (int r = 0; r < 4; ++r) li[r] = 1.0f / __shfl(l, lq * 4 + r);
    int b = hid >> 4, h = hid & 15;
    size_t orow_base = ((size_t)b * S_ + qt0 + lq * 4) * E_ + h * D_;
#pragma unroll
    for (int r = 0; r < 4; ++r) {
        size_t rb = orow_base + (size_t)r * E_;
        ab[rb + 0  + lr] = f2bf(o0[r] * li[r]);
        ab[rb + 16 + lr] = f2bf(o1[r] * li[r]);
        ab[rb + 32 + lr] = f2bf(o2[r] * li[r]);
        ab[rb + 48 + lr] = f2bf(o3[r] * li[r]);
    }
}

// ---------------- top-8 tiles from last-row logits (fp32 path) ----------------
__global__ __launch_bounds__(256) void topk_kernel(const float* __restrict__ qlast,
                                                   const float* __restrict__ kf,
                                                   const float* __restrict__ kres,
                                                   const float* __restrict__ cost,
                                                   const float* __restrict__ sint,
                                                   float* __restrict__ oidx) {
    __shared__ float qr[64];
    __shared__ float lmax[256];
    __shared__ float tmax[128];
    int bx = blockIdx.x;            // b*16 + h
    int h = bx & 15, b = bx >> 4;
    int tid = threadIdx.x;
    if (tid < 32) {
        float c = cost[2047 * 32 + tid], sn = sint[2047 * 32 + tid];
        float q0 = qlast[(size_t)b * E_ + h * 64 + 2 * tid];
        float q1 = qlast[(size_t)b * E_ + h * 64 + 2 * tid + 1];
        qr[2 * tid]     = q0 * c - q1 * sn;
        qr[2 * tid + 1] = q0 * sn + q1 * c;
    }
    __syncthreads();
    float best = -1e30f;
    for (int j = 0; j < 8; ++j) {
        int s = tid * 8 + j;
        size_t kbase = ((size_t)b * S_ + s) * E_ + h * 64;
        const float* kr  = &kf[kbase];
        const float* krr = &kres[kbase];
        float acc = 0.f;
#pragma unroll
        for (int i = 0; i < 32; ++i) {
            float c = cost[s * 32 + i], sn = sint[s * 32 + i];
            float k0 = kr[2 * i] + krr[2 * i];
            float k1 = kr[2 * i + 1] + krr[2 * i + 1];
            acc += qr[2 * i] * (k0 * c - k1 * sn) + qr[2 * i + 1] * (k0 * sn + k1 * c);
        }
        best = fmaxf(best, acc);
    }
    lmax[tid] = best;
    __syncthreads();
    if (tid < 128) tmax[tid] = fmaxf(lmax[2 * tid], lmax[2 * tid + 1]);
    __syncthreads();
    if (tid < 64) {                  // wave-parallel top-8 with lowest-index tiebreak
        float v0 = tmax[tid], v1 = tmax[tid + 64];
        float va, vb; int ia, ib;
        if (v1 > v0) { va = v1; ia = tid + 64; vb = v0; ib = tid; }
        else         { va = v0; ia = tid;      vb = v1; ib = tid + 64; }
        float cv = va; int ci = ia; int used = 0;
        for (int t = 0; t < 8; ++t) {
            float bv = cv; int bi = ci;
#pragma unroll
            for (int mk = 1; mk < 64; mk <<= 1) {
                float ov = __shfl_xor(bv, mk);
                int oi = __shfl_xor(bi, mk);
                if (ov > bv || (ov == bv && oi < bi)) { bv = ov; bi = oi; }
            }
            if (tid == 0) oidx[bx * 8 + t] = (float)bi;
            if (ci == bi) {
                if (used == 0) { cv = vb; ci = ib; used = 1; }
                else           { cv = -3e30f; ci = 1 << 20; }
            }
        }
    }
}

// ---------------- launch ----------------
extern "C" void kernel_launch(void* const* d_in, const int* in_sizes, int n_in,
                              void* d_out, int out_size, void* d_ws, size_t ws_size,
                              hipStream_t stream) {
    (void)in_sizes; (void)n_in; (void)out_size; (void)ws_size;
    const float* x  = (const float*)d_in[0];
    const float* wq = (const float*)d_in[1];
    const float* wk = (const float*)d_in[2];
    const float* wv = (const float*)d_in[3];
    const float* wo = (const float*)d_in[4];
    float* out = (float*)d_out;

    char* wsp = (char*)d_ws;
    size_t off = 0;
    auto nxt = [&](size_t bytes) {
        char* p = wsp + off;
        off = (off + bytes + 255) & ~(size_t)255;
        return p;
    };
    u16* xcat  = (u16*)nxt((size_t)BS_ * 2048 * 2);
    u16* wqt   = (u16*)nxt((size_t)E_ * E_ * 2);
    u16* wkt   = (u16*)nxt((size_t)E_ * E_ * 2);
    u16* wkres = (u16*)nxt((size_t)E_ * 2048 * 2);
    u16* wvt   = (u16*)nxt((size_t)E_ * E_ * 2);
    u16* wot   = (u16*)nxt((size_t)E_ * E_ * 2);
    float* qf  = (float*)nxt((size_t)BS_ * E_ * 4);
    float* kf  = (float*)nxt((size_t)BS_ * E_ * 4);
    float* kres = (float*)nxt((size_t)BS_ * E_ * 4);
    float* vf  = (float*)nxt((size_t)BS_ * E_ * 4);
    float* cost = (float*)nxt((size_t)S_ * 32 * 4);
    float* sint = (float*)nxt((size_t)S_ * 32 * 4);
    u16* qb    = (u16*)nxt((size_t)B_ * H_ * S_ * D_ * 2);
    u16* kb    = (u16*)nxt((size_t)B_ * H_ * S_ * D_ * 2);
    u16* vtb   = (u16*)nxt((size_t)B_ * H_ * S_ * D_ * 2);
    u16* ab    = (u16*)nxt((size_t)BS_ * E_ * 2);
    float* qlast = (float*)nxt((size_t)B_ * E_ * 4);

    // prep
    hipLaunchKernelGGL(rope_table_kernel, dim3(S_ * 32 / 256), dim3(256), 0, stream, cost, sint);
    hipLaunchKernelGGL(convert_x_kernel, dim3(BS_ * E_ / 4 / 256), dim3(256), 0, stream, x, xcat);
    hipLaunchKernelGGL(transpose_w_kernel, dim3(1024), dim3(256), 0, stream, wq, wqt, (u16*)nullptr);
    hipLaunchKernelGGL(transpose_w_kernel, dim3(1024), dim3(256), 0, stream, wk, wkt, wkres);
    hipLaunchKernelGGL(transpose_w_kernel, dim3(1024), dim3(256), 0, stream, wv, wvt, (u16*)nullptr);
    hipLaunchKernelGGL(transpose_w_kernel, dim3(1024), dim3(256), 0, stream, wo, wot, (u16*)nullptr);

    // 4-pass projections (K correction fused into one Kd=2048 pass)
    hipLaunchKernelGGL(proj_gemm_kernel, dim3(1024), dim3(256), 0, stream,
                       xcat, wqt, wkt, wkres, wvt, qf, kf, kres, vf);
    hipLaunchKernelGGL(qlast_kernel, dim3(64), dim3(256), 0, stream, x, wq, qlast);

    // rearrange
    hipLaunchKernelGGL(rope_qk_kernel, dim3(B_ * S_ * H_ * 32 / 256), dim3(256), 0, stream,
                       qf, kf, kres, cost, sint, qb, kb);
    hipLaunchKernelGGL(v_transpose_kernel, dim3(B_ * H_ * (S_ / 64)), dim3(256), 0, stream, vf, vtb);

    // attention + top-k
    hipLaunchKernelGGL(flash_kernel, dim3(B_ * H_ * (S_ / 64)), dim3(256), 0, stream, qb, kb, vtb, ab);
    hipLaunchKernelGGL(topk_kernel, dim3(B_ * H_), dim3(256), 0, stream,
                       qlast, kf, kres, cost, sint, out + (size_t)BS_ * E_);

    // output projection
    hipLaunchKernelGGL(gemm_bf16_kernel, dim3(256), dim3(256), 0, stream, ab, wot, out,
                       BS_, E_, E_);
}

// Round 6
// 245.803 us; speedup vs baseline: 1.9456x; 1.5749x over previous
//
#include <hip/hip_runtime.h>

#define B_ 2
#define S_ 2048
#define E_ 1024
#define H_ 16
#define D_ 64
#define BS_ (B_*S_)
#define PSTR 76   // flash P-lds stride in u16

typedef unsigned short u16;
typedef __attribute__((ext_vector_type(8))) short short8;
typedef __attribute__((ext_vector_type(4))) float floatx4;
typedef __bf16 bf16x8 __attribute__((ext_vector_type(8)));

__device__ __forceinline__ u16 f2bf(float f) {
    unsigned int u = __builtin_bit_cast(unsigned int, f);
    u += 0x7FFFu + ((u >> 16) & 1u);
    return (u16)(u >> 16);
}
__device__ __forceinline__ float bf2f(u16 h) {
    return __builtin_bit_cast(float, (unsigned int)h << 16);
}
__device__ __forceinline__ floatx4 mfma16(short8 a, short8 b, floatx4 c) {
    return __builtin_amdgcn_mfma_f32_16x16x32_bf16(
        __builtin_bit_cast(bf16x8, a), __builtin_bit_cast(bf16x8, b), c, 0, 0, 0);
}
__device__ __forceinline__ void gload_lds16(const void* g, void* l) {
    __builtin_amdgcn_global_load_lds(
        (const __attribute__((address_space(1))) unsigned int*)g,
        (__attribute__((address_space(3))) unsigned int*)l, 16, 0, 0);
}

// ---------------- prep kernels ----------------

__global__ __launch_bounds__(256) void rope_table_kernel(float* __restrict__ cost,
                                                         float* __restrict__ sint) {
    int idx = blockIdx.x * 256 + threadIdx.x;   // S_*32
    int s = idx >> 5, i = idx & 31;
    float inv = powf(10000.0f, -(float)i / 32.0f);
    float a = (float)s * inv;
    cost[idx] = cosf(a);
    sint[idx] = sinf(a);
}

// x fp32 -> xcat[row][2048] bf16: cols 0..1023 = hi(x), 1024..2047 = lo residual
__global__ __launch_bounds__(256) void convert_x_kernel(const float* __restrict__ X,
                                                        u16* __restrict__ xcat) {
    int i = blockIdx.x * 256 + threadIdx.x;     // BS_*E_/4 float4s
    int row = i >> 8, c4 = (i & 255) * 4;
    float4 v = ((const float4*)X)[i];
    u16 h0 = f2bf(v.x), h1 = f2bf(v.y), h2 = f2bf(v.z), h3 = f2bf(v.w);
    uint2 o;
    o.x = (unsigned)h0 | ((unsigned)h1 << 16);
    o.y = (unsigned)h2 | ((unsigned)h3 << 16);
    *(uint2*)&xcat[(size_t)row * 2048 + c4] = o;
    u16 l0 = f2bf(v.x - bf2f(h0)), l1 = f2bf(v.y - bf2f(h1));
    u16 l2 = f2bf(v.z - bf2f(h2)), l3 = f2bf(v.w - bf2f(h3));
    uint2 ol;
    ol.x = (unsigned)l0 | ((unsigned)l1 << 16);
    ol.y = (unsigned)l2 | ((unsigned)l3 << 16);
    *(uint2*)&xcat[(size_t)row * 2048 + 1024 + c4] = ol;
}

// all 4 weights in one launch. W [K][N] fp32 -> Wt [N][K] bf16; wk also -> Wres [N][2048]=[lo|hi]
__global__ __launch_bounds__(256) void transpose_w4_kernel(const float* __restrict__ wq,
                                                           const float* __restrict__ wk,
                                                           const float* __restrict__ wv,
                                                           const float* __restrict__ wo,
                                                           u16* __restrict__ wqt,
                                                           u16* __restrict__ wkt,
                                                           u16* __restrict__ wkres,
                                                           u16* __restrict__ wvt,
                                                           u16* __restrict__ wot) {
    __shared__ float t[32][33];
    int bx = blockIdx.x;
    int which = bx >> 10, sub = bx & 1023;
    const float* W = which == 0 ? wq : which == 1 ? wk : which == 2 ? wv : wo;
    u16* Wt = which == 0 ? wqt : which == 1 ? wkt : which == 2 ? wvt : wot;
    int tk = (sub >> 5) * 32, tn = (sub & 31) * 32;
    int tx = threadIdx.x & 31, ty = threadIdx.x >> 5;   // 32 x 8
    for (int i = 0; i < 32; i += 8)
        t[ty + i][tx] = W[(size_t)(tk + ty + i) * E_ + tn + tx];
    __syncthreads();
    for (int i = 0; i < 32; i += 8) {
        float v = t[tx][ty + i];
        u16 hi = f2bf(v);
        Wt[(size_t)(tn + ty + i) * E_ + tk + tx] = hi;
        if (which == 1) {
            wkres[(size_t)(tn + ty + i) * 2048 + tk + tx] = f2bf(v - bf2f(hi));
            wkres[(size_t)(tn + ty + i) * 2048 + 1024 + tk + tx] = hi;
        }
    }
}

// ---------------- GEMM core: 128x128 tile, gload_lds staging, T2 XOR-swizzled LDS ----------------
// LDS [128][64] u16; chunk j of row r holds global col-chunk j^(r&7) (pre-swizzled global src,
// linear LDS dest — rule #21). Read at chunk kc reads LDS chunk kc^(row&7): conflict-free.

__device__ __forceinline__ void stage_swz(const u16* __restrict__ src, int row0, int k0,
                                          int stride, u16* lds, int tid) {
    int wv = tid >> 6, ln = tid & 63;
    int swz = (((ln & 7) ^ (ln >> 3)) << 3);   // global col offset (u16) for this lane
    int rr = ln >> 3;
#pragma unroll
    for (int i = 0; i < 4; ++i) {
        int seg = i * 4 + wv;                  // 0..15 ; LDS dest = base + lane*16
        gload_lds16(&src[(size_t)(row0 + seg * 8 + rr) * stride + k0 + swz],
                    (char*)lds + (size_t)seg * 1024);
    }
}

__device__ __forceinline__ void gemm_body(const u16* lA, const u16* lB,
                                          floatx4 (*acc)[4], int lane, int wave) {
    int wm = (wave >> 1) * 64, wn = (wave & 1) * 64;
    int lr = lane & 15, lq = lane >> 4, r7 = lr & 7;
#pragma unroll
    for (int half = 0; half < 2; ++half) {
        int xo = (((half * 4 + lq) ^ r7) << 3);
        short8 afr[4], bfr[4];
#pragma unroll
        for (int mi = 0; mi < 4; ++mi)
            afr[mi] = *(const short8*)&lA[(wm + mi * 16 + lr) * 64 + xo];
#pragma unroll
        for (int ni = 0; ni < 4; ++ni)
            bfr[ni] = *(const short8*)&lB[(wn + ni * 16 + lr) * 64 + xo];
        __builtin_amdgcn_s_setprio(1);
#pragma unroll
        for (int mi = 0; mi < 4; ++mi)
#pragma unroll
            for (int ni = 0; ni < 4; ++ni)
                acc[mi][ni] = mfma16(afr[mi], bfr[ni], acc[mi][ni]);
        __builtin_amdgcn_s_setprio(0);
    }
}

__device__ __forceinline__ void gemm_write(float* __restrict__ C, floatx4 (*acc)[4],
                                           int m0, int n0, int N, int lane, int wave) {
    int wm = (wave >> 1) * 64, wn = (wave & 1) * 64;
    int lr = lane & 15, lq = lane >> 4;
#pragma unroll
    for (int mi = 0; mi < 4; ++mi)
#pragma unroll
        for (int ni = 0; ni < 4; ++ni)
#pragma unroll
            for (int r = 0; r < 4; ++r)
                C[(size_t)(m0 + wm + mi * 16 + lq * 4 + r) * N + n0 + wn + ni * 16 + lr]
                    = acc[mi][ni][r];
}

// RoPE epilogue: rotate adjacent-column lane pairs, write bf16 [bh][s][64] (+ optional fp32)
__device__ __forceinline__ void rope_epilogue(floatx4 (*acc)[4], int m0, int n0,
                                              const float* __restrict__ cost,
                                              const float* __restrict__ sint,
                                              u16* __restrict__ dstb,
                                              float* __restrict__ dstf,
                                              int lane, int wave) {
    int wm = (wave >> 1) * 64, wn = (wave & 1) * 64;
    int lr = lane & 15, lq = lane >> 4;
    int odd = lr & 1;
    int h = (n0 + wn) >> 6;
#pragma unroll
    for (int ni = 0; ni < 4; ++ni) {
        int d = ni * 16 + lr;
        int i = d >> 1;
#pragma unroll
        for (int mi = 0; mi < 4; ++mi) {
#pragma unroll
            for (int r = 0; r < 4; ++r) {
                int row = m0 + wm + mi * 16 + lq * 4 + r;
                int s = row & 2047, bq = row >> 11;
                float own = acc[mi][ni][r];
                float par = __shfl_xor(own, 1);
                float e = odd ? par : own;
                float o = odd ? own : par;
                float c = cost[s * 32 + i], sn = sint[s * 32 + i];
                float out = odd ? (e * sn + o * c) : (e * c - o * sn);
                size_t off = (((size_t)(bq * 16 + h)) * S_ + s) * 64 + d;
                dstb[off] = f2bf(out);
                if (dstf) dstf[off] = out;
            }
        }
    }
}

// V epilogue: LDS-bounce transpose -> vtb [bh][d][s] bf16 (pad-136 rows: conflict-free)
__device__ __forceinline__ void v_epilogue(floatx4 (*acc)[4], int m0, int n0,
                                           u16* vt, u16* __restrict__ vtb,
                                           int lane, int wave, int tid) {
    int wm = (wave >> 1) * 64, wn = (wave & 1) * 64;
    int lr = lane & 15, lq = lane >> 4;
#pragma unroll
    for (int ni = 0; ni < 4; ++ni) {
        int dcol = wn + ni * 16 + lr;
#pragma unroll
        for (int mi = 0; mi < 4; ++mi)
#pragma unroll
            for (int r = 0; r < 4; ++r)
                vt[dcol * 136 + wm + mi * 16 + lq * 4 + r] = f2bf(acc[mi][ni][r]);
    }
    __syncthreads();
    int dcol = tid >> 1, sh = (tid & 1) * 64;
    int colg = n0 + dcol, h = colg >> 6, d = colg & 63;
    int bq = m0 >> 11, s0 = m0 & 2047;
    size_t base = (((size_t)(bq * 16 + h)) * 64 + d) * S_ + s0 + sh;
#pragma unroll
    for (int c = 0; c < 8; ++c)
        *(uint4*)&vtb[base + c * 8] = *(const uint4*)&vt[dcol * 136 + sh + c * 8];
}

// fused projections: 768 blocks. role 0 (first 256, 3x work): K = x_hi@wk_hi + x_hi@wk_lo
// + x_lo@wk_hi -> rope -> kb bf16 + klogf fp32. role 1: Q -> rope -> qb. role 2: V -> vtb^T.
__global__ __launch_bounds__(256) void proj_gemm_kernel(const u16* __restrict__ xcat,
                                                        const u16* __restrict__ wqt,
                                                        const u16* __restrict__ wkt,
                                                        const u16* __restrict__ wkres,
                                                        const u16* __restrict__ wvt,
                                                        const float* __restrict__ cost,
                                                        const float* __restrict__ sint,
                                                        u16* __restrict__ qb,
                                                        u16* __restrict__ kb,
                                                        float* __restrict__ klogf,
                                                        u16* __restrict__ vtb) {
    __shared__ __align__(16) u16 lsbuf[17408];   // lA(8192) + lB(8192); reused as vt[128][136]
    u16* lA = lsbuf;
    u16* lB = lsbuf + 8192;
    int bx = blockIdx.x;
    int role = bx >> 8;                          // K first (longest)
    int idx = bx & 255;
    int m0 = (idx >> 3) * 128, n0 = (idx & 7) * 128;   // n0 pinned per XCD (idx&7)
    int tid = threadIdx.x, lane = tid & 63, wave = tid >> 6;

    floatx4 acc[4][4];
#pragma unroll
    for (int i = 0; i < 4; ++i)
#pragma unroll
        for (int j = 0; j < 4; ++j) acc[i][j] = (floatx4){0.f, 0.f, 0.f, 0.f};

    if (role == 0) {
        for (int k0 = 0; k0 < 1024; k0 += 64) {
            stage_swz(xcat, m0, k0, 2048, lA, tid);
            stage_swz(wkt, n0, k0, 1024, lB, tid);
            __syncthreads();
            gemm_body(lA, lB, acc, lane, wave);
            __syncthreads();
        }
        for (int k0 = 0; k0 < 2048; k0 += 64) {
            stage_swz(xcat, m0, k0, 2048, lA, tid);
            stage_swz(wkres, n0, k0, 2048, lB, tid);
            __syncthreads();
            gemm_body(lA, lB, acc, lane, wave);
            __syncthreads();
        }
        rope_epilogue(acc, m0, n0, cost, sint, kb, klogf, lane, wave);
    } else if (role == 1) {
        for (int k0 = 0; k0 < 1024; k0 += 64) {
            stage_swz(xcat, m0, k0, 2048, lA, tid);
            stage_swz(wqt, n0, k0, 1024, lB, tid);
            __syncthreads();
            gemm_body(lA, lB, acc, lane, wave);
            __syncthreads();
        }
        rope_epilogue(acc, m0, n0, cost, sint, qb, (float*)nullptr, lane, wave);
    } else {
        for (int k0 = 0; k0 < 1024; k0 += 64) {
            stage_swz(xcat, m0, k0, 2048, lA, tid);
            stage_swz(wvt, n0, k0, 1024, lB, tid);
            __syncthreads();
            gemm_body(lA, lB, acc, lane, wave);
            __syncthreads();
        }
        v_epilogue(acc, m0, n0, lsbuf, vtb, lane, wave, tid);
    }
}

// plain GEMM (output projection): C[M][N] = A[M][K] @ Bt[N][K]^T
__global__ __launch_bounds__(256) void gemm_bf16_kernel(const u16* __restrict__ A,
                                                        const u16* __restrict__ Bt,
                                                        float* __restrict__ C,
                                                        int M, int N, int Kd) {
    __shared__ __align__(16) u16 lA[128 * 64];
    __shared__ __align__(16) u16 lB[128 * 64];
    int nwg = (M / 128) * (N / 128);
    int bx = blockIdx.x;
    int q = nwg >> 3, rr = nwg & 7, xcd = bx & 7, pos = bx >> 3;
    int lbx = (xcd < rr ? xcd * (q + 1) : rr * (q + 1) + (xcd - rr) * q) + pos;
    int nbn = N / 128;
    int m0 = (lbx / nbn) * 128, n0 = (lbx % nbn) * 128;
    int tid = threadIdx.x, lane = tid & 63, wave = tid >> 6;

    floatx4 acc[4][4];
#pragma unroll
    for (int i = 0; i < 4; ++i)
#pragma unroll
        for (int j = 0; j < 4; ++j) acc[i][j] = (floatx4){0.f, 0.f, 0.f, 0.f};

    for (int k0 = 0; k0 < Kd; k0 += 64) {
        stage_swz(A, m0, k0, Kd, lA, tid);
        stage_swz(Bt, n0, k0, Kd, lB, tid);
        __syncthreads();
        gemm_body(lA, lB, acc, lane, wave);
        __syncthreads();
    }
    gemm_write(C, acc, m0, n0, N, lane, wave);
}

// ---------------- fp32 q for the last token (exact path for top-k) ----------------
__global__ __launch_bounds__(256) void qlast_kernel(const float* __restrict__ x,
                                                    const float* __restrict__ wq,
                                                    float* __restrict__ qlast) {
    __shared__ float red[8][32];
    int bx = blockIdx.x;
    int b = bx >> 5, c0 = (bx & 31) * 32;
    int cl = threadIdx.x & 31, kc = threadIdx.x >> 5;
    const float* xr = &x[((size_t)b * S_ + (S_ - 1)) * E_ + kc * 128];
    const float* wp = &wq[(size_t)(kc * 128) * E_ + c0 + cl];
    float acc = 0.f;
#pragma unroll 4
    for (int e = 0; e < 128; ++e) acc = fmaf(xr[e], wp[(size_t)e * E_], acc);
    red[kc][cl] = acc;
    __syncthreads();
    if (kc == 0) {
        float s = ((red[0][cl] + red[1][cl]) + (red[2][cl] + red[3][cl]))
                + ((red[4][cl] + red[5][cl]) + (red[6][cl] + red[7][cl]));
        qlast[(size_t)b * E_ + c0 + cl] = s;
    }
}

// ---------------- flash attention: LDS-DMA staged K/V, fragment-major segs ----------------
__device__ __forceinline__ void stage_kv(const u16* __restrict__ K, const u16* __restrict__ V,
                                         int n0, u16* kbuf, u16* vbuf, int wave, int lane) {
    int lr = lane & 15, lq = lane >> 4;
    if (wave < 2) {
#pragma unroll
        for (int i = 0; i < 4; ++i) {
            int sk = wave * 4 + i;            // seg = kt*2 + kh
            int kt = sk >> 1, kh = (sk & 1) * 32;
            gload_lds16(&K[(size_t)(n0 + kt * 16 + lr) * D_ + kh + lq * 8],
                        kbuf + sk * 512);
        }
    } else {
#pragma unroll
        for (int i = 0; i < 4; ++i) {
            int sv = (wave - 2) * 4 + i;      // seg = c*4 + o
            int c = sv >> 2, o = sv & 3;
            gload_lds16(&V[(size_t)(o * 16 + lr) * S_ + n0 + c * 32 + lq * 8],
                        vbuf + sv * 512);
        }
    }
}

__global__ __launch_bounds__(256) void flash_kernel(const u16* __restrict__ qb,
                                                    const u16* __restrict__ kb,
                                                    const u16* __restrict__ vtb,
                                                    u16* __restrict__ ab) {
    __shared__ __align__(16) u16 kls[2][8 * 512];
    __shared__ __align__(16) u16 vls[2][8 * 512];
    __shared__ __align__(16) u16 ldsP[4][16 * PSTR];
    int tid = threadIdx.x;
    int lane = tid & 63, wave = tid >> 6;
    int bx = blockIdx.x;
    int xcd = bx & 7, ii = bx >> 3;
    int hid = xcd + 8 * (ii & 3);   // 4 heads per XCD -> K/V L2-resident
    int qc = 31 - (ii >> 2);        // longest q-chunks dispatch first
    int qt0 = qc * 64 + wave * 16;
    const u16* Q = qb + (size_t)hid * S_ * D_;
    const u16* K = kb + (size_t)hid * S_ * D_;
    const u16* V = vtb + (size_t)hid * D_ * S_;
    u16* lp = &ldsP[wave][0];
    int lr = lane & 15, lq = lane >> 4, lk = lq * 8;

    short8 qfr0 = *(const short8*)&Q[(size_t)(qt0 + lr) * D_ + lk];
    short8 qfr1 = *(const short8*)&Q[(size_t)(qt0 + lr) * D_ + 32 + lk];

    floatx4 o0 = {0,0,0,0}, o1 = {0,0,0,0}, o2 = {0,0,0,0}, o3 = {0,0,0,0};
    float m = -1e30f, l = 0.f;

    stage_kv(K, V, 0, kls[0], vls[0], wave, lane);
    asm volatile("s_waitcnt vmcnt(0)" ::: "memory");
    __syncthreads();

    for (int it = 0; it <= qc; ++it) {
        int n0 = it * 64;
        int buf = it & 1;
        const u16* kbuf = kls[buf];
        const u16* vbuf = vls[buf];
        if (it < qc)
            stage_kv(K, V, n0 + 64, kls[buf ^ 1], vls[buf ^ 1], wave, lane);

        short8 ka0[4], ka1[4];
#pragma unroll
        for (int kt = 0; kt < 4; ++kt) {
            ka0[kt] = *(const short8*)&kbuf[(kt * 2 + 0) * 512 + lane * 8];
            ka1[kt] = *(const short8*)&kbuf[(kt * 2 + 1) * 512 + lane * 8];
        }
        floatx4 st[4];
#pragma unroll
        for (int kt = 0; kt < 4; ++kt) st[kt] = (floatx4){0.f, 0.f, 0.f, 0.f};
        __builtin_amdgcn_s_setprio(1);
#pragma unroll
        for (int kt = 0; kt < 4; ++kt) {
            st[kt] = mfma16(ka0[kt], qfr0, st[kt]);
            st[kt] = mfma16(ka1[kt], qfr1, st[kt]);
        }
        __builtin_amdgcn_s_setprio(0);

        const float SC = 0.18033688011112042f;   // 0.125 * log2(e)
        int rem = qt0 + 16 - n0;
        float sv[4][4];
        float bmax = -1e30f;
        if (rem >= 80) {
#pragma unroll
            for (int kt = 0; kt < 4; ++kt)
#pragma unroll
                for (int r = 0; r < 4; ++r) {
                    float s = st[kt][r] * SC;
                    sv[kt][r] = s;
                    bmax = fmaxf(bmax, s);
                }
        } else {
#pragma unroll
            for (int kt = 0; kt < 4; ++kt)
#pragma unroll
                for (int r = 0; r < 4; ++r) {
                    int k = n0 + kt * 16 + lq * 4 + r;
                    float s = (k <= qt0 + lr) ? st[kt][r] * SC : -1e30f;
                    sv[kt][r] = s;
                    bmax = fmaxf(bmax, s);
                }
        }
        bmax = fmaxf(bmax, __shfl_xor(bmax, 16));
        bmax = fmaxf(bmax, __shfl_xor(bmax, 32));
        if (!__all(bmax <= m + 8.0f)) {
            float mn = fmaxf(m, bmax);
            float alpha = __builtin_amdgcn_exp2f(m - mn);
            m = mn;
            l *= alpha;
            float af[4];
#pragma unroll
            for (int r = 0; r < 4; ++r) af[r] = __shfl(alpha, lq * 4 + r);
#pragma unroll
            for (int r = 0; r < 4; ++r) {
                o0[r] *= af[r]; o1[r] *= af[r]; o2[r] *= af[r]; o3[r] *= af[r];
            }
        }
        float ps = 0.f;
#pragma unroll
        for (int kt = 0; kt < 4; ++kt) {
            float p0 = __builtin_amdgcn_exp2f(sv[kt][0] - m);
            float p1 = __builtin_amdgcn_exp2f(sv[kt][1] - m);
            float p2 = __builtin_amdgcn_exp2f(sv[kt][2] - m);
            float p3 = __builtin_amdgcn_exp2f(sv[kt][3] - m);
            ps += (p0 + p1) + (p2 + p3);
            unsigned wlo, whi;
            asm("v_cvt_pk_bf16_f32 %0, %1, %2" : "=v"(wlo) : "v"(p0), "v"(p1));
            asm("v_cvt_pk_bf16_f32 %0, %1, %2" : "=v"(whi) : "v"(p2), "v"(p3));
            *(uint2*)&lp[lr * PSTR + kt * 16 + lq * 4] = (uint2){wlo, whi};
        }
        ps += __shfl_xor(ps, 16);
        ps += __shfl_xor(ps, 32);
        l += ps;

        short8 vv[2][4];
#pragma unroll
        for (int c = 0; c < 2; ++c)
#pragma unroll
            for (int o = 0; o < 4; ++o)
                vv[c][o] = *(const short8*)&vbuf[(c * 4 + o) * 512 + lane * 8];
        asm volatile("s_waitcnt lgkmcnt(0)" ::: "memory");
        __builtin_amdgcn_s_setprio(1);
#pragma unroll
        for (int c = 0; c < 2; ++c) {
            uint2 plo = *(const uint2*)&lp[lr * PSTR + c * 32 + lk];
            uint2 phi = *(const uint2*)&lp[lr * PSTR + c * 32 + lk + 4];
            short8 pfr = __builtin_bit_cast(short8, (uint4){plo.x, plo.y, phi.x, phi.y});
            o0 = mfma16(pfr, vv[c][0], o0);
            o1 = mfma16(pfr, vv[c][1], o1);
            o2 = mfma16(pfr, vv[c][2], o2);
            o3 = mfma16(pfr, vv[c][3], o3);
        }
        __builtin_amdgcn_s_setprio(0);

        if (it < qc) {
            asm volatile("s_waitcnt vmcnt(0)" ::: "memory");
            __syncthreads();
        }
    }
    float li[4];
#pragma unroll
    for (int r = 0; r < 4; ++r) li[r] = 1.0f / __shfl(l, lq * 4 + r);
    int b = hid >> 4, h = hid & 15;
    size_t orow_base = ((size_t)b * S_ + qt0 + lq * 4) * E_ + h * D_;
#pragma unroll
    for (int r = 0; r < 4; ++r) {
        size_t rb = orow_base + (size_t)r * E_;
        ab[rb + 0  + lr] = f2bf(o0[r] * li[r]);
        ab[rb + 16 + lr] = f2bf(o1[r] * li[r]);
        ab[rb + 32 + lr] = f2bf(o2[r] * li[r]);
        ab[rb + 48 + lr] = f2bf(o3[r] * li[r]);
    }
}

// ---------------- top-k: parallel tile scores from post-RoPE fp32 K logits ----------------
__global__ __launch_bounds__(256) void topk_scores_kernel(const float* __restrict__ qlast,
                                                          const float* __restrict__ klogf,
                                                          const float* __restrict__ cost,
                                                          const float* __restrict__ sint,
                                                          float* __restrict__ tscores) {
    __shared__ float qr[64];
    __shared__ float lmax[256];
    int bx = blockIdx.x;            // bh*8 + chunk
    int chunk = bx & 7, bh = bx >> 3;
    int b = bh >> 4, h = bh & 15;
    int tid = threadIdx.x;
    if (tid < 32) {
        float c = cost[2047 * 32 + tid], sn = sint[2047 * 32 + tid];
        float q0 = qlast[(size_t)b * E_ + h * 64 + 2 * tid];
        float q1 = qlast[(size_t)b * E_ + h * 64 + 2 * tid + 1];
        qr[2 * tid]     = q0 * c - q1 * sn;
        qr[2 * tid + 1] = q0 * sn + q1 * c;
    }
    __syncthreads();
    int s = chunk * 256 + tid;
    const float4* kr = (const float4*)&klogf[((size_t)bh * S_ + s) * 64];
    float acc = 0.f;
#pragma unroll
    for (int i = 0; i < 16; ++i) {
        float4 kv = kr[i];
        acc += qr[4*i] * kv.x + qr[4*i+1] * kv.y + qr[4*i+2] * kv.z + qr[4*i+3] * kv.w;
    }
    lmax[tid] = acc;
    __syncthreads();
    if (tid < 16) {
        float mx = lmax[tid * 16];
#pragma unroll
        for (int j = 1; j < 16; ++j) mx = fmaxf(mx, lmax[tid * 16 + j]);
        tscores[bh * 128 + chunk * 16 + tid] = mx;
    }
}

__global__ __launch_bounds__(64) void topk_select_kernel(const float* __restrict__ tscores,
                                                         float* __restrict__ oidx) {
    int bh = blockIdx.x, tid = threadIdx.x;
    float v0 = tscores[bh * 128 + tid], v1 = tscores[bh * 128 + 64 + tid];
    float va, vb; int ia, ib;
    if (v1 > v0) { va = v1; ia = tid + 64; vb = v0; ib = tid; }
    else         { va = v0; ia = tid;      vb = v1; ib = tid + 64; }
    float cv = va; int ci = ia; int used = 0;
    for (int t = 0; t < 8; ++t) {
        float bv = cv; int bi = ci;
#pragma unroll
        for (int mk = 1; mk < 64; mk <<= 1) {
            float ov = __shfl_xor(bv, mk);
            int oi = __shfl_xor(bi, mk);
            if (ov > bv || (ov == bv && oi < bi)) { bv = ov; bi = oi; }
        }
        if (tid == 0) oidx[bh * 8 + t] = (float)bi;
        if (ci == bi) {
            if (used == 0) { cv = vb; ci = ib; used = 1; }
            else           { cv = -3e30f; ci = 1 << 20; }
        }
    }
}

// ---------------- launch ----------------
extern "C" void kernel_launch(void* const* d_in, const int* in_sizes, int n_in,
                              void* d_out, int out_size, void* d_ws, size_t ws_size,
                              hipStream_t stream) {
    (void)in_sizes; (void)n_in; (void)out_size; (void)ws_size;
    const float* x  = (const float*)d_in[0];
    const float* wq = (const float*)d_in[1];
    const float* wk = (const float*)d_in[2];
    const float* wv = (const float*)d_in[3];
    const float* wo = (const float*)d_in[4];
    float* out = (float*)d_out;

    char* wsp = (char*)d_ws;
    size_t off = 0;
    auto nxt = [&](size_t bytes) {
        char* p = wsp + off;
        off = (off + bytes + 255) & ~(size_t)255;
        return p;
    };
    u16* xcat  = (u16*)nxt((size_t)BS_ * 2048 * 2);
    u16* wqt   = (u16*)nxt((size_t)E_ * E_ * 2);
    u16* wkt   = (u16*)nxt((size_t)E_ * E_ * 2);
    u16* wkres = (u16*)nxt((size_t)E_ * 2048 * 2);
    u16* wvt   = (u16*)nxt((size_t)E_ * E_ * 2);
    u16* wot   = (u16*)nxt((size_t)E_ * E_ * 2);
    float* cost = (float*)nxt((size_t)S_ * 32 * 4);
    float* sint = (float*)nxt((size_t)S_ * 32 * 4);
    u16* qb    = (u16*)nxt((size_t)B_ * H_ * S_ * D_ * 2);
    u16* kb    = (u16*)nxt((size_t)B_ * H_ * S_ * D_ * 2);
    float* klogf = (float*)nxt((size_t)B_ * H_ * S_ * D_ * 4);
    u16* vtb   = (u16*)nxt((size_t)B_ * H_ * S_ * D_ * 2);
    u16* ab    = (u16*)nxt((size_t)BS_ * E_ * 2);
    float* qlast = (float*)nxt((size_t)B_ * E_ * 4);
    float* tscores = (float*)nxt((size_t)B_ * H_ * 128 * 4);

    // prep
    hipLaunchKernelGGL(rope_table_kernel, dim3(S_ * 32 / 256), dim3(256), 0, stream, cost, sint);
    hipLaunchKernelGGL(convert_x_kernel, dim3(BS_ * E_ / 4 / 256), dim3(256), 0, stream, x, xcat);
    hipLaunchKernelGGL(transpose_w4_kernel, dim3(4096), dim3(256), 0, stream,
                       wq, wk, wv, wo, wqt, wkt, wkres, wvt, wot);

    // fused projections: RoPE + layout epilogues (no fp32 intermediates)
    hipLaunchKernelGGL(proj_gemm_kernel, dim3(768), dim3(256), 0, stream,
                       xcat, wqt, wkt, wkres, wvt, cost, sint, qb, kb, klogf, vtb);
    hipLaunchKernelGGL(qlast_kernel, dim3(64), dim3(256), 0, stream, x, wq, qlast);

    // attention
    hipLaunchKernelGGL(flash_kernel, dim3(B_ * H_ * (S_ / 64)), dim3(256), 0, stream,
                       qb, kb, vtb, ab);

    // top-k (parallel scores + tiny select)
    hipLaunchKernelGGL(topk_scores_kernel, dim3(B_ * H_ * 8), dim3(256), 0, stream,
                       qlast, klogf, cost, sint, tscores);
    hipLaunchKernelGGL(topk_select_kernel, dim3(B_ * H_), dim3(64), 0, stream,
                       tscores, out + (size_t)BS_ * E_);

    // output projection
    hipLaunchKernelGGL(gemm_bf16_kernel, dim3(256), dim3(256), 0, stream, ab, wot, out,
                       BS_, E_, E_);
}

// Round 9
// 223.160 us; speedup vs baseline: 2.1430x; 1.1015x over previous
//
#include <hip/hip_runtime.h>

#define B_ 2
#define S_ 2048
#define E_ 1024
#define H_ 16
#define D_ 64
#define BS_ (B_*S_)
#define PSTR 76   // flash P-lds stride in u16

typedef unsigned short u16;
typedef __attribute__((ext_vector_type(8))) short short8;
typedef __attribute__((ext_vector_type(4))) float floatx4;
typedef __bf16 bf16x8 __attribute__((ext_vector_type(8)));

__device__ __forceinline__ u16 f2bf(float f) {
    unsigned int u = __builtin_bit_cast(unsigned int, f);
    u += 0x7FFFu + ((u >> 16) & 1u);
    return (u16)(u >> 16);
}
__device__ __forceinline__ float bf2f(u16 h) {
    return __builtin_bit_cast(float, (unsigned int)h << 16);
}
__device__ __forceinline__ floatx4 mfma16(short8 a, short8 b, floatx4 c) {
    return __builtin_amdgcn_mfma_f32_16x16x32_bf16(
        __builtin_bit_cast(bf16x8, a), __builtin_bit_cast(bf16x8, b), c, 0, 0, 0);
}
__device__ __forceinline__ void gload_lds16(const void* g, void* l) {
    __builtin_amdgcn_global_load_lds(
        (const __attribute__((address_space(1))) unsigned int*)g,
        (__attribute__((address_space(3))) unsigned int*)l, 16, 0, 0);
}

// ---------------- prep kernels ----------------

__global__ __launch_bounds__(256) void rope_table_kernel(float* __restrict__ cost,
                                                         float* __restrict__ sint) {
    int idx = blockIdx.x * 256 + threadIdx.x;   // S_*32
    int s = idx >> 5, i = idx & 31;
    float inv = powf(10000.0f, -(float)i / 32.0f);
    float a = (float)s * inv;
    cost[idx] = cosf(a);
    sint[idx] = sinf(a);
}

// x fp32 -> xcat[row][2048] bf16: cols 0..1023 = hi(x), 1024..2047 = lo residual
__global__ __launch_bounds__(256) void convert_x_kernel(const float* __restrict__ X,
                                                        u16* __restrict__ xcat) {
    int i = blockIdx.x * 256 + threadIdx.x;     // BS_*E_/4 float4s
    int row = i >> 8, c4 = (i & 255) * 4;
    float4 v = ((const float4*)X)[i];
    u16 h0 = f2bf(v.x), h1 = f2bf(v.y), h2 = f2bf(v.z), h3 = f2bf(v.w);
    uint2 o;
    o.x = (unsigned)h0 | ((unsigned)h1 << 16);
    o.y = (unsigned)h2 | ((unsigned)h3 << 16);
    *(uint2*)&xcat[(size_t)row * 2048 + c4] = o;
    u16 l0 = f2bf(v.x - bf2f(h0)), l1 = f2bf(v.y - bf2f(h1));
    u16 l2 = f2bf(v.z - bf2f(h2)), l3 = f2bf(v.w - bf2f(h3));
    uint2 ol;
    ol.x = (unsigned)l0 | ((unsigned)l1 << 16);
    ol.y = (unsigned)l2 | ((unsigned)l3 << 16);
    *(uint2*)&xcat[(size_t)row * 2048 + 1024 + c4] = ol;
}

// all 4 weights in one launch. W [K][N] fp32 -> Wt [N][K] bf16; wk also -> Wres [N][2048]=[lo|hi]
__global__ __launch_bounds__(256) void transpose_w4_kernel(const float* __restrict__ wq,
                                                           const float* __restrict__ wk,
                                                           const float* __restrict__ wv,
                                                           const float* __restrict__ wo,
                                                           u16* __restrict__ wqt,
                                                           u16* __restrict__ wkt,
                                                           u16* __restrict__ wkres,
                                                           u16* __restrict__ wvt,
                                                           u16* __restrict__ wot) {
    __shared__ float t[32][33];
    int bx = blockIdx.x;
    int which = bx >> 10, sub = bx & 1023;
    const float* W = which == 0 ? wq : which == 1 ? wk : which == 2 ? wv : wo;
    u16* Wt = which == 0 ? wqt : which == 1 ? wkt : which == 2 ? wvt : wot;
    int tk = (sub >> 5) * 32, tn = (sub & 31) * 32;
    int tx = threadIdx.x & 31, ty = threadIdx.x >> 5;   // 32 x 8
    for (int i = 0; i < 32; i += 8)
        t[ty + i][tx] = W[(size_t)(tk + ty + i) * E_ + tn + tx];
    __syncthreads();
    for (int i = 0; i < 32; i += 8) {
        float v = t[tx][ty + i];
        u16 hi = f2bf(v);
        Wt[(size_t)(tn + ty + i) * E_ + tk + tx] = hi;
        if (which == 1) {
            wkres[(size_t)(tn + ty + i) * 2048 + tk + tx] = f2bf(v - bf2f(hi));
            wkres[(size_t)(tn + ty + i) * 2048 + 1024 + tk + tx] = hi;
        }
    }
}

// ---------------- GEMM core: 128x128 tile, gload_lds staging, T2 XOR-swizzled LDS ----------------

__device__ __forceinline__ void stage_swz(const u16* __restrict__ src, int row0, int k0,
                                          int stride, u16* lds, int tid) {
    int wv = tid >> 6, ln = tid & 63;
    int swz = (((ln & 7) ^ (ln >> 3)) << 3);   // global col offset (u16) for this lane
    int rr = ln >> 3;
#pragma unroll
    for (int i = 0; i < 4; ++i) {
        int seg = i * 4 + wv;                  // 0..15 ; LDS dest = base + lane*16
        gload_lds16(&src[(size_t)(row0 + seg * 8 + rr) * stride + k0 + swz],
                    (char*)lds + (size_t)seg * 1024);
    }
}

__device__ __forceinline__ void gemm_body(const u16* lA, const u16* lB,
                                          floatx4 (*acc)[4], int lane, int wave) {
    int wm = (wave >> 1) * 64, wn = (wave & 1) * 64;
    int lr = lane & 15, lq = lane >> 4, r7 = lr & 7;
#pragma unroll
    for (int half = 0; half < 2; ++half) {
        int xo = (((half * 4 + lq) ^ r7) << 3);
        short8 afr[4], bfr[4];
#pragma unroll
        for (int mi = 0; mi < 4; ++mi)
            afr[mi] = *(const short8*)&lA[(wm + mi * 16 + lr) * 64 + xo];
#pragma unroll
        for (int ni = 0; ni < 4; ++ni)
            bfr[ni] = *(const short8*)&lB[(wn + ni * 16 + lr) * 64 + xo];
        __builtin_amdgcn_s_setprio(1);
#pragma unroll
        for (int mi = 0; mi < 4; ++mi)
#pragma unroll
            for (int ni = 0; ni < 4; ++ni)
                acc[mi][ni] = mfma16(afr[mi], bfr[ni], acc[mi][ni]);
        __builtin_amdgcn_s_setprio(0);
    }
}

__device__ __forceinline__ void gemm_write(float* __restrict__ C, floatx4 (*acc)[4],
                                           int m0, int n0, int N, int lane, int wave) {
    int wm = (wave >> 1) * 64, wn = (wave & 1) * 64;
    int lr = lane & 15, lq = lane >> 4;
#pragma unroll
    for (int mi = 0; mi < 4; ++mi)
#pragma unroll
        for (int ni = 0; ni < 4; ++ni)
#pragma unroll
            for (int r = 0; r < 4; ++r)
                C[(size_t)(m0 + wm + mi * 16 + lq * 4 + r) * N + n0 + wn + ni * 16 + lr]
                    = acc[mi][ni][r];
}

// RoPE epilogue: rotate adjacent-column lane pairs, write bf16 [bh][s][64].
// K role (qlast != null): also computes exact fp32 last-token logits in-register and
// reduces them to per-16-tile maxima -> tscores (kills the klogf buffer + extra kernel).
__device__ __forceinline__ void rope_epilogue(floatx4 (*acc)[4], int m0, int n0,
                                              const float* __restrict__ cost,
                                              const float* __restrict__ sint,
                                              const float* __restrict__ qlast,
                                              u16* __restrict__ dstb,
                                              float* __restrict__ tscores,
                                              int lane, int wave) {
    int wm = (wave >> 1) * 64, wn = (wave & 1) * 64;
    int lr = lane & 15, lq = lane >> 4;
    int odd = lr & 1;
    int h = (n0 + wn) >> 6;
    int bq = m0 >> 11;
    int s0 = m0 & 2047;
    float qr[4];
    if (qlast) {
#pragma unroll
        for (int ni = 0; ni < 4; ++ni) {
            int d = ni * 16 + lr;
            int i = d >> 1;
            float qv = qlast[(size_t)bq * E_ + h * 64 + d];
            float qp = __shfl_xor(qv, 1);
            float c = cost[2047 * 32 + i], sn = sint[2047 * 32 + i];
            qr[ni] = odd ? (qp * sn + qv * c) : (qv * c - qp * sn);
        }
    }
    float dotp[4][4];
#pragma unroll
    for (int mi = 0; mi < 4; ++mi)
#pragma unroll
        for (int r = 0; r < 4; ++r) dotp[mi][r] = 0.f;
#pragma unroll
    for (int ni = 0; ni < 4; ++ni) {
        int d = ni * 16 + lr;
        int i = d >> 1;
#pragma unroll
        for (int mi = 0; mi < 4; ++mi) {
#pragma unroll
            for (int r = 0; r < 4; ++r) {
                int row = m0 + wm + mi * 16 + lq * 4 + r;
                int s = row & 2047;
                float own = acc[mi][ni][r];
                float par = __shfl_xor(own, 1);
                float c = cost[s * 32 + i], sn = sint[s * 32 + i];
                float out = odd ? (par * sn + own * c) : (own * c - par * sn);
                dstb[(((size_t)(bq * 16 + h)) * S_ + s) * 64 + d] = f2bf(out);
                if (qlast) dotp[mi][r] += out * qr[ni];
            }
        }
    }
    if (qlast) {
#pragma unroll
        for (int mi = 0; mi < 4; ++mi) {
            float tm = -1e30f;
#pragma unroll
            for (int r = 0; r < 4; ++r) {
                float dv = dotp[mi][r];
                dv += __shfl_xor(dv, 1);
                dv += __shfl_xor(dv, 2);
                dv += __shfl_xor(dv, 4);
                dv += __shfl_xor(dv, 8);
                tm = fmaxf(tm, dv);           // dv = full dot for row lq*4+r of this tile
            }
            tm = fmaxf(tm, __shfl_xor(tm, 16));
            tm = fmaxf(tm, __shfl_xor(tm, 32));
            // tile index within this (b,h): from s0 (batch-local), NOT global m0
            if (lane == 0)
                tscores[(size_t)(bq * 16 + h) * 128 + (s0 >> 4) + (wm >> 4) + mi] = tm;
        }
    }
}

// V epilogue: LDS-bounce transpose -> vtb [bh][d][s] bf16 (pad-136 rows: conflict-free)
__device__ __forceinline__ void v_epilogue(floatx4 (*acc)[4], int m0, int n0,
                                           u16* vt, u16* __restrict__ vtb,
                                           int lane, int wave, int tid) {
    int wm = (wave >> 1) * 64, wn = (wave & 1) * 64;
    int lr = lane & 15, lq = lane >> 4;
#pragma unroll
    for (int ni = 0; ni < 4; ++ni) {
        int dcol = wn + ni * 16 + lr;
#pragma unroll
        for (int mi = 0; mi < 4; ++mi)
#pragma unroll
            for (int r = 0; r < 4; ++r)
                vt[dcol * 136 + wm + mi * 16 + lq * 4 + r] = f2bf(acc[mi][ni][r]);
    }
    __syncthreads();
    int dcol = tid >> 1, sh = (tid & 1) * 64;
    int colg = n0 + dcol, h = colg >> 6, d = colg & 63;
    int bq = m0 >> 11, s0 = m0 & 2047;
    size_t base = (((size_t)(bq * 16 + h)) * 64 + d) * S_ + s0 + sh;
#pragma unroll
    for (int c = 0; c < 8; ++c)
        *(uint4*)&vtb[base + c * 8] = *(const uint4*)&vt[dcol * 136 + sh + c * 8];
}

// fused projections: 768 blocks, m-strips pinned per XCD (A stays L2-resident).
// role 0 (first, 3x work): K = x_hi@wk_hi + x_hi@wk_lo + x_lo@wk_hi -> rope -> kb + tscores.
// role 1: Q -> rope -> qb. role 2: V -> vtb^T.
__global__ __launch_bounds__(256) void proj_gemm_kernel(const u16* __restrict__ xcat,
                                                        const u16* __restrict__ wqt,
                                                        const u16* __restrict__ wkt,
                                                        const u16* __restrict__ wkres,
                                                        const u16* __restrict__ wvt,
                                                        const float* __restrict__ cost,
                                                        const float* __restrict__ sint,
                                                        const float* __restrict__ qlast,
                                                        u16* __restrict__ qb,
                                                        u16* __restrict__ kb,
                                                        float* __restrict__ tscores,
                                                        u16* __restrict__ vtb) {
    __shared__ __align__(16) u16 lsbuf[17408];   // lA(8192) + lB(8192); reused as vt[128][136]
    u16* lA = lsbuf;
    u16* lB = lsbuf + 8192;
    int bx = blockIdx.x;
    int role = bx >> 8;                          // K first (longest)
    int idx = bx & 255;
    int xcd = idx & 7, loc = idx >> 3;           // XCD = bx%8 = idx&7
    int m0 = (xcd * 4 + (loc & 3)) * 128;        // 4 m-strips pinned per XCD (2MB of xcat)
    int n0 = (loc >> 2) * 128;
    int tid = threadIdx.x, lane = tid & 63, wave = tid >> 6;

    floatx4 acc[4][4];
#pragma unroll
    for (int i = 0; i < 4; ++i)
#pragma unroll
        for (int j = 0; j < 4; ++j) acc[i][j] = (floatx4){0.f, 0.f, 0.f, 0.f};

    if (role == 0) {
        for (int k0 = 0; k0 < 1024; k0 += 64) {
            stage_swz(xcat, m0, k0, 2048, lA, tid);
            stage_swz(wkt, n0, k0, 1024, lB, tid);
            __syncthreads();
            gemm_body(lA, lB, acc, lane, wave);
            __syncthreads();
        }
        for (int k0 = 0; k0 < 2048; k0 += 64) {
            stage_swz(xcat, m0, k0, 2048, lA, tid);
            stage_swz(wkres, n0, k0, 2048, lB, tid);
            __syncthreads();
            gemm_body(lA, lB, acc, lane, wave);
            __syncthreads();
        }
        rope_epilogue(acc, m0, n0, cost, sint, qlast, kb, tscores, lane, wave);
    } else if (role == 1) {
        for (int k0 = 0; k0 < 1024; k0 += 64) {
            stage_swz(xcat, m0, k0, 2048, lA, tid);
            stage_swz(wqt, n0, k0, 1024, lB, tid);
            __syncthreads();
            gemm_body(lA, lB, acc, lane, wave);
            __syncthreads();
        }
        rope_epilogue(acc, m0, n0, cost, sint, (const float*)nullptr, qb,
                      (float*)nullptr, lane, wave);
    } else {
        for (int k0 = 0; k0 < 1024; k0 += 64) {
            stage_swz(xcat, m0, k0, 2048, lA, tid);
            stage_swz(wvt, n0, k0, 1024, lB, tid);
            __syncthreads();
            gemm_body(lA, lB, acc, lane, wave);
            __syncthreads();
        }
        v_epilogue(acc, m0, n0, lsbuf, vtb, lane, wave, tid);
    }
}

// plain GEMM (output projection): C[M][N] = A[M][K] @ Bt[N][K]^T
__global__ __launch_bounds__(256) void gemm_bf16_kernel(const u16* __restrict__ A,
                                                        const u16* __restrict__ Bt,
                                                        float* __restrict__ C,
                                                        int M, int N, int Kd) {
    __shared__ __align__(16) u16 lA[128 * 64];
    __shared__ __align__(16) u16 lB[128 * 64];
    int nwg = (M / 128) * (N / 128);
    int bx = blockIdx.x;
    int q = nwg >> 3, rr = nwg & 7, xcd = bx & 7, pos = bx >> 3;
    int lbx = (xcd < rr ? xcd * (q + 1) : rr * (q + 1) + (xcd - rr) * q) + pos;
    int nbn = N / 128;
    int m0 = (lbx / nbn) * 128, n0 = (lbx % nbn) * 128;
    int tid = threadIdx.x, lane = tid & 63, wave = tid >> 6;

    floatx4 acc[4][4];
#pragma unroll
    for (int i = 0; i < 4; ++i)
#pragma unroll
        for (int j = 0; j < 4; ++j) acc[i][j] = (floatx4){0.f, 0.f, 0.f, 0.f};

    for (int k0 = 0; k0 < Kd; k0 += 64) {
        stage_swz(A, m0, k0, Kd, lA, tid);
        stage_swz(Bt, n0, k0, Kd, lB, tid);
        __syncthreads();
        gemm_body(lA, lB, acc, lane, wave);
        __syncthreads();
    }
    gemm_write(C, acc, m0, n0, N, lane, wave);
}

// ---------------- fp32 q for the last token (exact path for top-k) ----------------
__global__ __launch_bounds__(256) void qlast_kernel(const float* __restrict__ x,
                                                    const float* __restrict__ wq,
                                                    float* __restrict__ qlast) {
    __shared__ float red[8][32];
    int bx = blockIdx.x;
    int b = bx >> 5, c0 = (bx & 31) * 32;
    int cl = threadIdx.x & 31, kc = threadIdx.x >> 5;
    const float* xr = &x[((size_t)b * S_ + (S_ - 1)) * E_ + kc * 128];
    const float* wp = &wq[(size_t)(kc * 128) * E_ + c0 + cl];
    float acc = 0.f;
#pragma unroll 4
    for (int e = 0; e < 128; ++e) acc = fmaf(xr[e], wp[(size_t)e * E_], acc);
    red[kc][cl] = acc;
    __syncthreads();
    if (kc == 0) {
        float s = ((red[0][cl] + red[1][cl]) + (red[2][cl] + red[3][cl]))
                + ((red[4][cl] + red[5][cl]) + (red[6][cl] + red[7][cl]));
        qlast[(size_t)b * E_ + c0 + cl] = s;
    }
}

// ---------------- flash attention: LDS-DMA staged K/V, fragment-major segs ----------------
__device__ __forceinline__ void stage_kv(const u16* __restrict__ K, const u16* __restrict__ V,
                                         int n0, u16* kbuf, u16* vbuf, int wave, int lane) {
    int lr = lane & 15, lq = lane >> 4;
    if (wave < 2) {
#pragma unroll
        for (int i = 0; i < 4; ++i) {
            int sk = wave * 4 + i;            // seg = kt*2 + kh
            int kt = sk >> 1, kh = (sk & 1) * 32;
            gload_lds16(&K[(size_t)(n0 + kt * 16 + lr) * D_ + kh + lq * 8],
                        kbuf + sk * 512);
        }
    } else {
#pragma unroll
        for (int i = 0; i < 4; ++i) {
            int sv = (wave - 2) * 4 + i;      // seg = c*4 + o
            int c = sv >> 2, o = sv & 3;
            gload_lds16(&V[(size_t)(o * 16 + lr) * S_ + n0 + c * 32 + lq * 8],
                        vbuf + sv * 512);
        }
    }
}

__global__ __launch_bounds__(256) void flash_kernel(const u16* __restrict__ qb,
                                                    const u16* __restrict__ kb,
                                                    const u16* __restrict__ vtb,
                                                    u16* __restrict__ ab) {
    __shared__ __align__(16) u16 kls[2][8 * 512];
    __shared__ __align__(16) u16 vls[2][8 * 512];
    __shared__ __align__(16) u16 ldsP[4][16 * PSTR];
    int tid = threadIdx.x;
    int lane = tid & 63, wave = tid >> 6;
    int bx = blockIdx.x;
    int xcd = bx & 7, ii = bx >> 3;
    int hid = xcd + 8 * (ii & 3);   // 4 heads per XCD -> K/V L2-resident
    int qc = 31 - (ii >> 2);        // longest q-chunks dispatch first
    int qt0 = qc * 64 + wave * 16;
    const u16* Q = qb + (size_t)hid * S_ * D_;
    const u16* K = kb + (size_t)hid * S_ * D_;
    const u16* V = vtb + (size_t)hid * D_ * S_;
    u16* lp = &ldsP[wave][0];
    int lr = lane & 15, lq = lane >> 4, lk = lq * 8;

    short8 qfr0 = *(const short8*)&Q[(size_t)(qt0 + lr) * D_ + lk];
    short8 qfr1 = *(const short8*)&Q[(size_t)(qt0 + lr) * D_ + 32 + lk];

    floatx4 o0 = {0,0,0,0}, o1 = {0,0,0,0}, o2 = {0,0,0,0}, o3 = {0,0,0,0};
    float m = -1e30f, l = 0.f;

    stage_kv(K, V, 0, kls[0], vls[0], wave, lane);
    asm volatile("s_waitcnt vmcnt(0)" ::: "memory");
    __syncthreads();

    for (int it = 0; it <= qc; ++it) {
        int n0 = it * 64;
        int buf = it & 1;
        const u16* kbuf = kls[buf];
        const u16* vbuf = vls[buf];
        if (it < qc)
            stage_kv(K, V, n0 + 64, kls[buf ^ 1], vls[buf ^ 1], wave, lane);

        short8 ka0[4], ka1[4];
#pragma unroll
        for (int kt = 0; kt < 4; ++kt) {
            ka0[kt] = *(const short8*)&kbuf[(kt * 2 + 0) * 512 + lane * 8];
            ka1[kt] = *(const short8*)&kbuf[(kt * 2 + 1) * 512 + lane * 8];
        }
        floatx4 st[4];
#pragma unroll
        for (int kt = 0; kt < 4; ++kt) st[kt] = (floatx4){0.f, 0.f, 0.f, 0.f};
        __builtin_amdgcn_s_setprio(1);
#pragma unroll
        for (int kt = 0; kt < 4; ++kt) {
            st[kt] = mfma16(ka0[kt], qfr0, st[kt]);
            st[kt] = mfma16(ka1[kt], qfr1, st[kt]);
        }
        __builtin_amdgcn_s_setprio(0);

        const float SC = 0.18033688011112042f;   // 0.125 * log2(e)
        int rem = qt0 + 16 - n0;
        float sv[4][4];
        float bmax = -1e30f;
        if (rem >= 80) {
#pragma unroll
            for (int kt = 0; kt < 4; ++kt)
#pragma unroll
                for (int r = 0; r < 4; ++r) {
                    float s = st[kt][r] * SC;
                    sv[kt][r] = s;
                    bmax = fmaxf(bmax, s);
                }
        } else {
#pragma unroll
            for (int kt = 0; kt < 4; ++kt)
#pragma unroll
                for (int r = 0; r < 4; ++r) {
                    int k = n0 + kt * 16 + lq * 4 + r;
                    float s = (k <= qt0 + lr) ? st[kt][r] * SC : -1e30f;
                    sv[kt][r] = s;
                    bmax = fmaxf(bmax, s);
                }
        }
        bmax = fmaxf(bmax, __shfl_xor(bmax, 16));
        bmax = fmaxf(bmax, __shfl_xor(bmax, 32));
        if (!__all(bmax <= m + 8.0f)) {
            float mn = fmaxf(m, bmax);
            float alpha = __builtin_amdgcn_exp2f(m - mn);
            m = mn;
            l *= alpha;
            float af[4];
#pragma unroll
            for (int r = 0; r < 4; ++r) af[r] = __shfl(alpha, lq * 4 + r);
#pragma unroll
            for (int r = 0; r < 4; ++r) {
                o0[r] *= af[r]; o1[r] *= af[r]; o2[r] *= af[r]; o3[r] *= af[r];
            }
        }
        float ps = 0.f;
#pragma unroll
        for (int kt = 0; kt < 4; ++kt) {
            float p0 = __builtin_amdgcn_exp2f(sv[kt][0] - m);
            float p1 = __builtin_amdgcn_exp2f(sv[kt][1] - m);
            float p2 = __builtin_amdgcn_exp2f(sv[kt][2] - m);
            float p3 = __builtin_amdgcn_exp2f(sv[kt][3] - m);
            ps += (p0 + p1) + (p2 + p3);
            unsigned wlo, whi;
            asm("v_cvt_pk_bf16_f32 %0, %1, %2" : "=v"(wlo) : "v"(p0), "v"(p1));
            asm("v_cvt_pk_bf16_f32 %0, %1, %2" : "=v"(whi) : "v"(p2), "v"(p3));
            *(uint2*)&lp[lr * PSTR + kt * 16 + lq * 4] = (uint2){wlo, whi};
        }
        ps += __shfl_xor(ps, 16);
        ps += __shfl_xor(ps, 32);
        l += ps;

        short8 vv[2][4];
#pragma unroll
        for (int c = 0; c < 2; ++c)
#pragma unroll
            for (int o = 0; o < 4; ++o)
                vv[c][o] = *(const short8*)&vbuf[(c * 4 + o) * 512 + lane * 8];
        asm volatile("s_waitcnt lgkmcnt(0)" ::: "memory");
        __builtin_amdgcn_s_setprio(1);
#pragma unroll
        for (int c = 0; c < 2; ++c) {
            uint2 plo = *(const uint2*)&lp[lr * PSTR + c * 32 + lk];
            uint2 phi = *(const uint2*)&lp[lr * PSTR + c * 32 + lk + 4];
            short8 pfr = __builtin_bit_cast(short8, (uint4){plo.x, plo.y, phi.x, phi.y});
            o0 = mfma16(pfr, vv[c][0], o0);
            o1 = mfma16(pfr, vv[c][1], o1);
            o2 = mfma16(pfr, vv[c][2], o2);
            o3 = mfma16(pfr, vv[c][3], o3);
        }
        __builtin_amdgcn_s_setprio(0);

        if (it < qc) {
            asm volatile("s_waitcnt vmcnt(0)" ::: "memory");
            __syncthreads();
        }
    }
    float li[4];
#pragma unroll
    for (int r = 0; r < 4; ++r) li[r] = 1.0f / __shfl(l, lq * 4 + r);
    int b = hid >> 4, h = hid & 15;
    size_t orow_base = ((size_t)b * S_ + qt0 + lq * 4) * E_ + h * D_;
#pragma unroll
    for (int r = 0; r < 4; ++r) {
        size_t rb = orow_base + (size_t)r * E_;
        ab[rb + 0  + lr] = f2bf(o0[r] * li[r]);
        ab[rb + 16 + lr] = f2bf(o1[r] * li[r]);
        ab[rb + 32 + lr] = f2bf(o2[r] * li[r]);
        ab[rb + 48 + lr] = f2bf(o3[r] * li[r]);
    }
}

// ---------------- top-8 select from precomputed tile scores ----------------
__global__ __launch_bounds__(64) void topk_select_kernel(const float* __restrict__ tscores,
                                                         float* __restrict__ oidx) {
    int bh = blockIdx.x, tid = threadIdx.x;
    float v0 = tscores[bh * 128 + tid], v1 = tscores[bh * 128 + 64 + tid];
    float va, vb; int ia, ib;
    if (v1 > v0) { va = v1; ia = tid + 64; vb = v0; ib = tid; }
    else         { va = v0; ia = tid;      vb = v1; ib = tid + 64; }
    float cv = va; int ci = ia; int used = 0;
    for (int t = 0; t < 8; ++t) {
        float bv = cv; int bi = ci;
#pragma unroll
        for (int mk = 1; mk < 64; mk <<= 1) {
            float ov = __shfl_xor(bv, mk);
            int oi = __shfl_xor(bi, mk);
            if (ov > bv || (ov == bv && oi < bi)) { bv = ov; bi = oi; }
        }
        if (tid == 0) oidx[bh * 8 + t] = (float)bi;
        if (ci == bi) {
            if (used == 0) { cv = vb; ci = ib; used = 1; }
            else           { cv = -3e30f; ci = 1 << 20; }
        }
    }
}

// ---------------- launch ----------------
extern "C" void kernel_launch(void* const* d_in, const int* in_sizes, int n_in,
                              void* d_out, int out_size, void* d_ws, size_t ws_size,
                              hipStream_t stream) {
    (void)in_sizes; (void)n_in; (void)out_size; (void)ws_size;
    const float* x  = (const float*)d_in[0];
    const float* wq = (const float*)d_in[1];
    const float* wk = (const float*)d_in[2];
    const float* wv = (const float*)d_in[3];
    const float* wo = (const float*)d_in[4];
    float* out = (float*)d_out;

    char* wsp = (char*)d_ws;
    size_t off = 0;
    auto nxt = [&](size_t bytes) {
        char* p = wsp + off;
        off = (off + bytes + 255) & ~(size_t)255;
        return p;
    };
    u16* xcat  = (u16*)nxt((size_t)BS_ * 2048 * 2);
    u16* wqt   = (u16*)nxt((size_t)E_ * E_ * 2);
    u16* wkt   = (u16*)nxt((size_t)E_ * E_ * 2);
    u16* wkres = (u16*)nxt((size_t)E_ * 2048 * 2);
    u16* wvt   = (u16*)nxt((size_t)E_ * E_ * 2);
    u16* wot   = (u16*)nxt((size_t)E_ * E_ * 2);
    float* cost = (float*)nxt((size_t)S_ * 32 * 4);
    float* sint = (float*)nxt((size_t)S_ * 32 * 4);
    u16* qb    = (u16*)nxt((size_t)B_ * H_ * S_ * D_ * 2);
    u16* kb    = (u16*)nxt((size_t)B_ * H_ * S_ * D_ * 2);
    u16* vtb   = (u16*)nxt((size_t)B_ * H_ * S_ * D_ * 2);
    u16* ab    = (u16*)nxt((size_t)BS_ * E_ * 2);
    float* qlast = (float*)nxt((size_t)B_ * E_ * 4);
    float* tscores = (float*)nxt((size_t)B_ * H_ * 128 * 4);

    // prep
    hipLaunchKernelGGL(rope_table_kernel, dim3(S_ * 32 / 256), dim3(256), 0, stream, cost, sint);
    hipLaunchKernelGGL(convert_x_kernel, dim3(BS_ * E_ / 4 / 256), dim3(256), 0, stream, x, xcat);
    hipLaunchKernelGGL(transpose_w4_kernel, dim3(4096), dim3(256), 0, stream,
                       wq, wk, wv, wo, wqt, wkt, wkres, wvt, wot);
    hipLaunchKernelGGL(qlast_kernel, dim3(64), dim3(256), 0, stream, x, wq, qlast);

    // fused projections: RoPE + V-transpose + top-k tile scores in the epilogues
    hipLaunchKernelGGL(proj_gemm_kernel, dim3(768), dim3(256), 0, stream,
                       xcat, wqt, wkt, wkres, wvt, cost, sint, qlast,
                       qb, kb, tscores, vtb);

    // attention
    hipLaunchKernelGGL(flash_kernel, dim3(B_ * H_ * (S_ / 64)), dim3(256), 0, stream,
                       qb, kb, vtb, ab);

    // top-k select (tiny)
    hipLaunchKernelGGL(topk_select_kernel, dim3(B_ * H_), dim3(64), 0, stream,
                       tscores, out + (size_t)BS_ * E_);

    // output projection
    hipLaunchKernelGGL(gemm_bf16_kernel, dim3(256), dim3(256), 0, stream, ab, wot, out,
                       BS_, E_, E_);
}

// Round 10
// 221.762 us; speedup vs baseline: 2.1566x; 1.0063x over previous
//
#include <hip/hip_runtime.h>

#define B_ 2
#define S_ 2048
#define E_ 1024
#define H_ 16
#define D_ 64
#define BS_ (B_*S_)
#define PSTR 76   // flash P-lds stride in u16

typedef unsigned short u16;
typedef __attribute__((ext_vector_type(8))) short short8;
typedef __attribute__((ext_vector_type(4))) float floatx4;
typedef __bf16 bf16x8 __attribute__((ext_vector_type(8)));

__device__ __forceinline__ u16 f2bf(float f) {
    unsigned int u = __builtin_bit_cast(unsigned int, f);
    u += 0x7FFFu + ((u >> 16) & 1u);
    return (u16)(u >> 16);
}
__device__ __forceinline__ float bf2f(u16 h) {
    return __builtin_bit_cast(float, (unsigned int)h << 16);
}
__device__ __forceinline__ floatx4 mfma16(short8 a, short8 b, floatx4 c) {
    return __builtin_amdgcn_mfma_f32_16x16x32_bf16(
        __builtin_bit_cast(bf16x8, a), __builtin_bit_cast(bf16x8, b), c, 0, 0, 0);
}
__device__ __forceinline__ void gload_lds16(const void* g, void* l) {
    __builtin_amdgcn_global_load_lds(
        (const __attribute__((address_space(1))) unsigned int*)g,
        (__attribute__((address_space(3))) unsigned int*)l, 16, 0, 0);
}

// ---------------- merged prep kernel (4 roles by block range) ----------------
// [0,4096): x -> xcat [row][2048] = [hi | lo]
// [4096,8192): W transpose (4 weights); wk also -> wkres [N][2048] = [lo | hi]
// [8192,8448): rope table
// [8448,8512): qlast fp32 (exact last-token q)
__global__ __launch_bounds__(256) void prep_kernel(const float* __restrict__ x,
                                                   const float* __restrict__ wq,
                                                   const float* __restrict__ wk,
                                                   const float* __restrict__ wv,
                                                   const float* __restrict__ wo,
                                                   u16* __restrict__ xcat,
                                                   u16* __restrict__ wqt,
                                                   u16* __restrict__ wkt,
                                                   u16* __restrict__ wkres,
                                                   u16* __restrict__ wvt,
                                                   u16* __restrict__ wot,
                                                   float* __restrict__ cost,
                                                   float* __restrict__ sint,
                                                   float* __restrict__ qlast) {
    __shared__ float t[32][33];
    int bx = blockIdx.x;
    int tid = threadIdx.x;
    if (bx < 4096) {
        int i = bx * 256 + tid;
        int row = i >> 8, c4 = (i & 255) * 4;
        float4 v = ((const float4*)x)[i];
        u16 h0 = f2bf(v.x), h1 = f2bf(v.y), h2 = f2bf(v.z), h3 = f2bf(v.w);
        uint2 o;
        o.x = (unsigned)h0 | ((unsigned)h1 << 16);
        o.y = (unsigned)h2 | ((unsigned)h3 << 16);
        *(uint2*)&xcat[(size_t)row * 2048 + c4] = o;
        u16 l0 = f2bf(v.x - bf2f(h0)), l1 = f2bf(v.y - bf2f(h1));
        u16 l2 = f2bf(v.z - bf2f(h2)), l3 = f2bf(v.w - bf2f(h3));
        uint2 ol;
        ol.x = (unsigned)l0 | ((unsigned)l1 << 16);
        ol.y = (unsigned)l2 | ((unsigned)l3 << 16);
        *(uint2*)&xcat[(size_t)row * 2048 + 1024 + c4] = ol;
    } else if (bx < 8192) {
        int sub = bx - 4096;
        int which = sub >> 10, s2 = sub & 1023;
        const float* W = which == 0 ? wq : which == 1 ? wk : which == 2 ? wv : wo;
        u16* Wt = which == 0 ? wqt : which == 1 ? wkt : which == 2 ? wvt : wot;
        int tk = (s2 >> 5) * 32, tn = (s2 & 31) * 32;
        int tx = tid & 31, ty = tid >> 5;   // 32 x 8
        for (int i = 0; i < 32; i += 8)
            t[ty + i][tx] = W[(size_t)(tk + ty + i) * E_ + tn + tx];
        __syncthreads();
        for (int i = 0; i < 32; i += 8) {
            float v = t[tx][ty + i];
            u16 hi = f2bf(v);
            Wt[(size_t)(tn + ty + i) * E_ + tk + tx] = hi;
            if (which == 1) {
                wkres[(size_t)(tn + ty + i) * 2048 + tk + tx] = f2bf(v - bf2f(hi));
                wkres[(size_t)(tn + ty + i) * 2048 + 1024 + tk + tx] = hi;
            }
        }
    } else if (bx < 8448) {
        int idx = (bx - 8192) * 256 + tid;   // S_*32
        int s = idx >> 5, i = idx & 31;
        float inv = powf(10000.0f, -(float)i / 32.0f);
        float a = (float)s * inv;
        cost[idx] = cosf(a);
        sint[idx] = sinf(a);
    } else {
        float* red = &t[0][0];               // reuse LDS (needs 256 floats)
        int b2 = bx - 8448;
        int b = b2 >> 5, c0 = (b2 & 31) * 32;
        int cl = tid & 31, kc = tid >> 5;
        const float* xr = &x[((size_t)b * S_ + (S_ - 1)) * E_ + kc * 128];
        const float* wp = &wq[(size_t)(kc * 128) * E_ + c0 + cl];
        float acc = 0.f;
#pragma unroll 4
        for (int e = 0; e < 128; ++e) acc = fmaf(xr[e], wp[(size_t)e * E_], acc);
        red[kc * 32 + cl] = acc;
        __syncthreads();
        if (kc == 0) {
            float s = ((red[0 * 32 + cl] + red[1 * 32 + cl]) + (red[2 * 32 + cl] + red[3 * 32 + cl]))
                    + ((red[4 * 32 + cl] + red[5 * 32 + cl]) + (red[6 * 32 + cl] + red[7 * 32 + cl]));
            qlast[(size_t)b * E_ + c0 + cl] = s;
        }
    }
}

// ---------------- GEMM core: 128x128 tile, gload_lds staging, T2 XOR-swizzled LDS ----------------

__device__ __forceinline__ void stage_swz(const u16* __restrict__ src, int row0, int k0,
                                          int stride, u16* lds, int tid) {
    int wv = tid >> 6, ln = tid & 63;
    int swz = (((ln & 7) ^ (ln >> 3)) << 3);   // global col offset (u16) for this lane
    int rr = ln >> 3;
#pragma unroll
    for (int i = 0; i < 4; ++i) {
        int seg = i * 4 + wv;                  // 0..15 ; LDS dest = base + lane*16
        gload_lds16(&src[(size_t)(row0 + seg * 8 + rr) * stride + k0 + swz],
                    (char*)lds + (size_t)seg * 1024);
    }
}

__device__ __forceinline__ void gemm_body(const u16* lA, const u16* lB,
                                          floatx4 (*acc)[4], int lane, int wave) {
    int wm = (wave >> 1) * 64, wn = (wave & 1) * 64;
    int lr = lane & 15, lq = lane >> 4, r7 = lr & 7;
#pragma unroll
    for (int half = 0; half < 2; ++half) {
        int xo = (((half * 4 + lq) ^ r7) << 3);
        short8 afr[4], bfr[4];
#pragma unroll
        for (int mi = 0; mi < 4; ++mi)
            afr[mi] = *(const short8*)&lA[(wm + mi * 16 + lr) * 64 + xo];
#pragma unroll
        for (int ni = 0; ni < 4; ++ni)
            bfr[ni] = *(const short8*)&lB[(wn + ni * 16 + lr) * 64 + xo];
        __builtin_amdgcn_s_setprio(1);
#pragma unroll
        for (int mi = 0; mi < 4; ++mi)
#pragma unroll
            for (int ni = 0; ni < 4; ++ni)
                acc[mi][ni] = mfma16(afr[mi], bfr[ni], acc[mi][ni]);
        __builtin_amdgcn_s_setprio(0);
    }
}

__device__ __forceinline__ void gemm_write(float* __restrict__ C, floatx4 (*acc)[4],
                                           int m0, int n0, int N, int lane, int wave) {
    int wm = (wave >> 1) * 64, wn = (wave & 1) * 64;
    int lr = lane & 15, lq = lane >> 4;
#pragma unroll
    for (int mi = 0; mi < 4; ++mi)
#pragma unroll
        for (int ni = 0; ni < 4; ++ni)
#pragma unroll
            for (int r = 0; r < 4; ++r)
                C[(size_t)(m0 + wm + mi * 16 + lq * 4 + r) * N + n0 + wn + ni * 16 + lr]
                    = acc[mi][ni][r];
}

// RoPE epilogue: rotate adjacent-column lane pairs, write bf16 [bh][s][64].
// K role (qlast != null): also fp32 last-token logits -> per-16-tile maxima -> tscores.
__device__ __forceinline__ void rope_epilogue(floatx4 (*acc)[4], int m0, int n0,
                                              const float* __restrict__ cost,
                                              const float* __restrict__ sint,
                                              const float* __restrict__ qlast,
                                              u16* __restrict__ dstb,
                                              float* __restrict__ tscores,
                                              int lane, int wave) {
    int wm = (wave >> 1) * 64, wn = (wave & 1) * 64;
    int lr = lane & 15, lq = lane >> 4;
    int odd = lr & 1;
    int h = (n0 + wn) >> 6;
    int bq = m0 >> 11;
    int s0 = m0 & 2047;
    float qr[4];
    if (qlast) {
#pragma unroll
        for (int ni = 0; ni < 4; ++ni) {
            int d = ni * 16 + lr;
            int i = d >> 1;
            float qv = qlast[(size_t)bq * E_ + h * 64 + d];
            float qp = __shfl_xor(qv, 1);
            float c = cost[2047 * 32 + i], sn = sint[2047 * 32 + i];
            qr[ni] = odd ? (qp * sn + qv * c) : (qv * c - qp * sn);
        }
    }
    float dotp[4][4];
#pragma unroll
    for (int mi = 0; mi < 4; ++mi)
#pragma unroll
        for (int r = 0; r < 4; ++r) dotp[mi][r] = 0.f;
#pragma unroll
    for (int ni = 0; ni < 4; ++ni) {
        int d = ni * 16 + lr;
        int i = d >> 1;
#pragma unroll
        for (int mi = 0; mi < 4; ++mi) {
#pragma unroll
            for (int r = 0; r < 4; ++r) {
                int row = m0 + wm + mi * 16 + lq * 4 + r;
                int s = row & 2047;
                float own = acc[mi][ni][r];
                float par = __shfl_xor(own, 1);
                float c = cost[s * 32 + i], sn = sint[s * 32 + i];
                float out = odd ? (par * sn + own * c) : (own * c - par * sn);
                dstb[(((size_t)(bq * 16 + h)) * S_ + s) * 64 + d] = f2bf(out);
                if (qlast) dotp[mi][r] += out * qr[ni];
            }
        }
    }
    if (qlast) {
#pragma unroll
        for (int mi = 0; mi < 4; ++mi) {
            float tm = -1e30f;
#pragma unroll
            for (int r = 0; r < 4; ++r) {
                float dv = dotp[mi][r];
                dv += __shfl_xor(dv, 1);
                dv += __shfl_xor(dv, 2);
                dv += __shfl_xor(dv, 4);
                dv += __shfl_xor(dv, 8);
                tm = fmaxf(tm, dv);
            }
            tm = fmaxf(tm, __shfl_xor(tm, 16));
            tm = fmaxf(tm, __shfl_xor(tm, 32));
            if (lane == 0)
                tscores[(size_t)(bq * 16 + h) * 128 + (s0 >> 4) + (wm >> 4) + mi] = tm;
        }
    }
}

// V epilogue: LDS-bounce transpose -> vtb [bh][d][s] bf16 (pad-136 rows)
__device__ __forceinline__ void v_epilogue(floatx4 (*acc)[4], int m0, int n0,
                                           u16* vt, u16* __restrict__ vtb,
                                           int lane, int wave, int tid) {
    int wm = (wave >> 1) * 64, wn = (wave & 1) * 64;
    int lr = lane & 15, lq = lane >> 4;
#pragma unroll
    for (int ni = 0; ni < 4; ++ni) {
        int dcol = wn + ni * 16 + lr;
#pragma unroll
        for (int mi = 0; mi < 4; ++mi)
#pragma unroll
            for (int r = 0; r < 4; ++r)
                vt[dcol * 136 + wm + mi * 16 + lq * 4 + r] = f2bf(acc[mi][ni][r]);
    }
    __syncthreads();
    int dcol = tid >> 1, sh = (tid & 1) * 64;
    int colg = n0 + dcol, h = colg >> 6, d = colg & 63;
    int bq = m0 >> 11, s0 = m0 & 2047;
    size_t base = (((size_t)(bq * 16 + h)) * 64 + d) * S_ + s0 + sh;
#pragma unroll
    for (int c = 0; c < 8; ++c)
        *(uint4*)&vtb[base + c * 8] = *(const uint4*)&vt[dcol * 136 + sh + c * 8];
}

// fused projections: 768 blocks, m-strips pinned per XCD.
// role 0: K (merged staging: 16 steps x {x_hi,x_lo,wk_hi,wk_lo} -> 3 gemm_body each).
// roles 1/2: Q / V, double-buffered 2-phase pipeline (stage-next-before-compute).
__global__ __launch_bounds__(256) void proj_gemm_kernel(const u16* __restrict__ xcat,
                                                        const u16* __restrict__ wqt,
                                                        const u16* __restrict__ wkt,
                                                        const u16* __restrict__ wkres,
                                                        const u16* __restrict__ wvt,
                                                        const float* __restrict__ cost,
                                                        const float* __restrict__ sint,
                                                        const float* __restrict__ qlast,
                                                        u16* __restrict__ qb,
                                                        u16* __restrict__ kb,
                                                        float* __restrict__ tscores,
                                                        u16* __restrict__ vtb) {
    __shared__ __align__(16) u16 lds4[4 * 8192];   // 64KB: 4 x 128x64 tiles; aliased as vt
    u16* T0 = lds4;
    u16* T1 = lds4 + 8192;
    u16* T2 = lds4 + 16384;
    u16* T3 = lds4 + 24576;
    int bx = blockIdx.x;
    int role = bx >> 8;                          // K first (longest)
    int idx = bx & 255;
    int xcd = idx & 7, loc = idx >> 3;
    int m0 = (xcd * 4 + (loc & 3)) * 128;        // m-strips pinned per XCD
    int n0 = (loc >> 2) * 128;
    int tid = threadIdx.x, lane = tid & 63, wave = tid >> 6;

    floatx4 acc[4][4];
#pragma unroll
    for (int i = 0; i < 4; ++i)
#pragma unroll
        for (int j = 0; j < 4; ++j) acc[i][j] = (floatx4){0.f, 0.f, 0.f, 0.f};

    if (role == 0) {
        // K: 16 steps, 4 tiles/step, 3 MFMA passes/step (96 MFMA per barrier pair)
        for (int k0 = 0; k0 < 1024; k0 += 64) {
            stage_swz(xcat, m0, k0, 2048, T0, tid);          // x_hi
            stage_swz(xcat, m0, k0 + 1024, 2048, T1, tid);   // x_lo
            stage_swz(wkt, n0, k0, 1024, T2, tid);           // wk_hi
            stage_swz(wkres, n0, k0, 2048, T3, tid);         // wk_lo
            asm volatile("s_waitcnt vmcnt(0)" ::: "memory");
            __syncthreads();
            gemm_body(T0, T2, acc, lane, wave);
            gemm_body(T0, T3, acc, lane, wave);
            gemm_body(T1, T2, acc, lane, wave);
            __syncthreads();
        }
        rope_epilogue(acc, m0, n0, cost, sint, qlast, kb, tscores, lane, wave);
    } else {
        const u16* Bt = (role == 1) ? wqt : wvt;
        // dbuf 2-phase: A in T0/T1, B in T2/T3
        stage_swz(xcat, m0, 0, 2048, T0, tid);
        stage_swz(Bt, n0, 0, 1024, T2, tid);
        asm volatile("s_waitcnt vmcnt(0)" ::: "memory");
        __syncthreads();
        for (int step = 0; step < 16; ++step) {
            int buf = step & 1;
            u16* Ac = buf ? T1 : T0;
            u16* Bc = buf ? T3 : T2;
            if (step < 15) {
                stage_swz(xcat, m0, (step + 1) * 64, 2048, buf ? T0 : T1, tid);
                stage_swz(Bt, n0, (step + 1) * 64, 1024, buf ? T2 : T3, tid);
            }
            gemm_body(Ac, Bc, acc, lane, wave);
            asm volatile("s_waitcnt vmcnt(0)" ::: "memory");
            __syncthreads();
        }
        if (role == 1)
            rope_epilogue(acc, m0, n0, cost, sint, (const float*)nullptr, qb,
                          (float*)nullptr, lane, wave);
        else
            v_epilogue(acc, m0, n0, lds4, vtb, lane, wave, tid);
    }
}

// output projection GEMM, dbuf 2-phase: C[M][N] = A[M][K] @ Bt[N][K]^T
__global__ __launch_bounds__(256) void gemm_bf16_kernel(const u16* __restrict__ A,
                                                        const u16* __restrict__ Bt,
                                                        float* __restrict__ C,
                                                        int M, int N, int Kd) {
    __shared__ __align__(16) u16 lds4[4 * 8192];
    u16* T0 = lds4;
    u16* T1 = lds4 + 8192;
    u16* T2 = lds4 + 16384;
    u16* T3 = lds4 + 24576;
    int nwg = (M / 128) * (N / 128);
    int bx = blockIdx.x;
    int q = nwg >> 3, rr = nwg & 7, xcd = bx & 7, pos = bx >> 3;
    int lbx = (xcd < rr ? xcd * (q + 1) : rr * (q + 1) + (xcd - rr) * q) + pos;
    int nbn = N / 128;
    int m0 = (lbx / nbn) * 128, n0 = (lbx % nbn) * 128;
    int tid = threadIdx.x, lane = tid & 63, wave = tid >> 6;

    floatx4 acc[4][4];
#pragma unroll
    for (int i = 0; i < 4; ++i)
#pragma unroll
        for (int j = 0; j < 4; ++j) acc[i][j] = (floatx4){0.f, 0.f, 0.f, 0.f};

    int nsteps = Kd / 64;
    stage_swz(A, m0, 0, Kd, T0, tid);
    stage_swz(Bt, n0, 0, Kd, T2, tid);
    asm volatile("s_waitcnt vmcnt(0)" ::: "memory");
    __syncthreads();
    for (int step = 0; step < nsteps; ++step) {
        int buf = step & 1;
        u16* Ac = buf ? T1 : T0;
        u16* Bc = buf ? T3 : T2;
        if (step + 1 < nsteps) {
            stage_swz(A, m0, (step + 1) * 64, Kd, buf ? T0 : T1, tid);
            stage_swz(Bt, n0, (step + 1) * 64, Kd, buf ? T2 : T3, tid);
        }
        gemm_body(Ac, Bc, acc, lane, wave);
        asm volatile("s_waitcnt vmcnt(0)" ::: "memory");
        __syncthreads();
    }
    gemm_write(C, acc, m0, n0, N, lane, wave);
}

// ---------------- flash attention: LDS-DMA staged K/V, fragment-major segs ----------------
__device__ __forceinline__ void stage_kv(const u16* __restrict__ K, const u16* __restrict__ V,
                                         int n0, u16* kbuf, u16* vbuf, int wave, int lane) {
    int lr = lane & 15, lq = lane >> 4;
    if (wave < 2) {
#pragma unroll
        for (int i = 0; i < 4; ++i) {
            int sk = wave * 4 + i;            // seg = kt*2 + kh
            int kt = sk >> 1, kh = (sk & 1) * 32;
            gload_lds16(&K[(size_t)(n0 + kt * 16 + lr) * D_ + kh + lq * 8],
                        kbuf + sk * 512);
        }
    } else {
#pragma unroll
        for (int i = 0; i < 4; ++i) {
            int sv = (wave - 2) * 4 + i;      // seg = c*4 + o
            int c = sv >> 2, o = sv & 3;
            gload_lds16(&V[(size_t)(o * 16 + lr) * S_ + n0 + c * 32 + lq * 8],
                        vbuf + sv * 512);
        }
    }
}

__global__ __launch_bounds__(256) void flash_kernel(const u16* __restrict__ qb,
                                                    const u16* __restrict__ kb,
                                                    const u16* __restrict__ vtb,
                                                    u16* __restrict__ ab) {
    __shared__ __align__(16) u16 kls[2][8 * 512];
    __shared__ __align__(16) u16 vls[2][8 * 512];
    __shared__ __align__(16) u16 ldsP[4][16 * PSTR];
    int tid = threadIdx.x;
    int lane = tid & 63, wave = tid >> 6;
    int bx = blockIdx.x;
    int xcd = bx & 7, ii = bx >> 3;
    int hid = xcd + 8 * (ii & 3);   // 4 heads per XCD -> K/V L2-resident
    int qc = 31 - (ii >> 2);        // longest q-chunks dispatch first
    int qt0 = qc * 64 + wave * 16;
    const u16* Q = qb + (size_t)hid * S_ * D_;
    const u16* K = kb + (size_t)hid * S_ * D_;
    const u16* V = vtb + (size_t)hid * D_ * S_;
    u16* lp = &ldsP[wave][0];
    int lr = lane & 15, lq = lane >> 4, lk = lq * 8;

    short8 qfr0 = *(const short8*)&Q[(size_t)(qt0 + lr) * D_ + lk];
    short8 qfr1 = *(const short8*)&Q[(size_t)(qt0 + lr) * D_ + 32 + lk];

    floatx4 o0 = {0,0,0,0}, o1 = {0,0,0,0}, o2 = {0,0,0,0}, o3 = {0,0,0,0};
    float m = -1e30f, l = 0.f;

    stage_kv(K, V, 0, kls[0], vls[0], wave, lane);
    asm volatile("s_waitcnt vmcnt(0)" ::: "memory");
    __syncthreads();

    for (int it = 0; it <= qc; ++it) {
        int n0 = it * 64;
        int buf = it & 1;
        const u16* kbuf = kls[buf];
        const u16* vbuf = vls[buf];
        if (it < qc)
            stage_kv(K, V, n0 + 64, kls[buf ^ 1], vls[buf ^ 1], wave, lane);

        short8 ka0[4], ka1[4];
#pragma unroll
        for (int kt = 0; kt < 4; ++kt) {
            ka0[kt] = *(const short8*)&kbuf[(kt * 2 + 0) * 512 + lane * 8];
            ka1[kt] = *(const short8*)&kbuf[(kt * 2 + 1) * 512 + lane * 8];
        }
        floatx4 st[4];
#pragma unroll
        for (int kt = 0; kt < 4; ++kt) st[kt] = (floatx4){0.f, 0.f, 0.f, 0.f};
        __builtin_amdgcn_s_setprio(1);
#pragma unroll
        for (int kt = 0; kt < 4; ++kt) {
            st[kt] = mfma16(ka0[kt], qfr0, st[kt]);
            st[kt] = mfma16(ka1[kt], qfr1, st[kt]);
        }
        __builtin_amdgcn_s_setprio(0);

        const float SC = 0.18033688011112042f;   // 0.125 * log2(e)
        int rem = qt0 + 16 - n0;
        float sv[4][4];
        float bmax = -1e30f;
        if (rem >= 80) {
#pragma unroll
            for (int kt = 0; kt < 4; ++kt)
#pragma unroll
                for (int r = 0; r < 4; ++r) {
                    float s = st[kt][r] * SC;
                    sv[kt][r] = s;
                    bmax = fmaxf(bmax, s);
                }
        } else {
#pragma unroll
            for (int kt = 0; kt < 4; ++kt)
#pragma unroll
                for (int r = 0; r < 4; ++r) {
                    int k = n0 + kt * 16 + lq * 4 + r;
                    float s = (k <= qt0 + lr) ? st[kt][r] * SC : -1e30f;
                    sv[kt][r] = s;
                    bmax = fmaxf(bmax, s);
                }
        }
        bmax = fmaxf(bmax, __shfl_xor(bmax, 16));
        bmax = fmaxf(bmax, __shfl_xor(bmax, 32));
        if (!__all(bmax <= m + 8.0f)) {
            float mn = fmaxf(m, bmax);
            float alpha = __builtin_amdgcn_exp2f(m - mn);
            m = mn;
            l *= alpha;
            float af[4];
#pragma unroll
            for (int r = 0; r < 4; ++r) af[r] = __shfl(alpha, lq * 4 + r);
#pragma unroll
            for (int r = 0; r < 4; ++r) {
                o0[r] *= af[r]; o1[r] *= af[r]; o2[r] *= af[r]; o3[r] *= af[r];
            }
        }
        float ps = 0.f;
#pragma unroll
        for (int kt = 0; kt < 4; ++kt) {
            float p0 = __builtin_amdgcn_exp2f(sv[kt][0] - m);
            float p1 = __builtin_amdgcn_exp2f(sv[kt][1] - m);
            float p2 = __builtin_amdgcn_exp2f(sv[kt][2] - m);
            float p3 = __builtin_amdgcn_exp2f(sv[kt][3] - m);
            ps += (p0 + p1) + (p2 + p3);
            unsigned wlo, whi;
            asm("v_cvt_pk_bf16_f32 %0, %1, %2" : "=v"(wlo) : "v"(p0), "v"(p1));
            asm("v_cvt_pk_bf16_f32 %0, %1, %2" : "=v"(whi) : "v"(p2), "v"(p3));
            *(uint2*)&lp[lr * PSTR + kt * 16 + lq * 4] = (uint2){wlo, whi};
        }
        ps += __shfl_xor(ps, 16);
        ps += __shfl_xor(ps, 32);
        l += ps;

        short8 vv[2][4];
#pragma unroll
        for (int c = 0; c < 2; ++c)
#pragma unroll
            for (int o = 0; o < 4; ++o)
                vv[c][o] = *(const short8*)&vbuf[(c * 4 + o) * 512 + lane * 8];
        asm volatile("s_waitcnt lgkmcnt(0)" ::: "memory");
        __builtin_amdgcn_s_setprio(1);
#pragma unroll
        for (int c = 0; c < 2; ++c) {
            uint2 plo = *(const uint2*)&lp[lr * PSTR + c * 32 + lk];
            uint2 phi = *(const uint2*)&lp[lr * PSTR + c * 32 + lk + 4];
            short8 pfr = __builtin_bit_cast(short8, (uint4){plo.x, plo.y, phi.x, phi.y});
            o0 = mfma16(pfr, vv[c][0], o0);
            o1 = mfma16(pfr, vv[c][1], o1);
            o2 = mfma16(pfr, vv[c][2], o2);
            o3 = mfma16(pfr, vv[c][3], o3);
        }
        __builtin_amdgcn_s_setprio(0);

        if (it < qc) {
            asm volatile("s_waitcnt vmcnt(0)" ::: "memory");
            __syncthreads();
        }
    }
    float li[4];
#pragma unroll
    for (int r = 0; r < 4; ++r) li[r] = 1.0f / __shfl(l, lq * 4 + r);
    int b = hid >> 4, h = hid & 15;
    size_t orow_base = ((size_t)b * S_ + qt0 + lq * 4) * E_ + h * D_;
#pragma unroll
    for (int r = 0; r < 4; ++r) {
        size_t rb = orow_base + (size_t)r * E_;
        ab[rb + 0  + lr] = f2bf(o0[r] * li[r]);
        ab[rb + 16 + lr] = f2bf(o1[r] * li[r]);
        ab[rb + 32 + lr] = f2bf(o2[r] * li[r]);
        ab[rb + 48 + lr] = f2bf(o3[r] * li[r]);
    }
}

// ---------------- top-8 select from precomputed tile scores ----------------
__global__ __launch_bounds__(64) void topk_select_kernel(const float* __restrict__ tscores,
                                                         float* __restrict__ oidx) {
    int bh = blockIdx.x, tid = threadIdx.x;
    float v0 = tscores[bh * 128 + tid], v1 = tscores[bh * 128 + 64 + tid];
    float va, vb; int ia, ib;
    if (v1 > v0) { va = v1; ia = tid + 64; vb = v0; ib = tid; }
    else         { va = v0; ia = tid;      vb = v1; ib = tid + 64; }
    float cv = va; int ci = ia; int used = 0;
    for (int t = 0; t < 8; ++t) {
        float bv = cv; int bi = ci;
#pragma unroll
        for (int mk = 1; mk < 64; mk <<= 1) {
            float ov = __shfl_xor(bv, mk);
            int oi = __shfl_xor(bi, mk);
            if (ov > bv || (ov == bv && oi < bi)) { bv = ov; bi = oi; }
        }
        if (tid == 0) oidx[bh * 8 + t] = (float)bi;
        if (ci == bi) {
            if (used == 0) { cv = vb; ci = ib; used = 1; }
            else           { cv = -3e30f; ci = 1 << 20; }
        }
    }
}

// ---------------- launch ----------------
extern "C" void kernel_launch(void* const* d_in, const int* in_sizes, int n_in,
                              void* d_out, int out_size, void* d_ws, size_t ws_size,
                              hipStream_t stream) {
    (void)in_sizes; (void)n_in; (void)out_size; (void)ws_size;
    const float* x  = (const float*)d_in[0];
    const float* wq = (const float*)d_in[1];
    const float* wk = (const float*)d_in[2];
    const float* wv = (const float*)d_in[3];
    const float* wo = (const float*)d_in[4];
    float* out = (float*)d_out;

    char* wsp = (char*)d_ws;
    size_t off = 0;
    auto nxt = [&](size_t bytes) {
        char* p = wsp + off;
        off = (off + bytes + 255) & ~(size_t)255;
        return p;
    };
    u16* xcat  = (u16*)nxt((size_t)BS_ * 2048 * 2);
    u16* wqt   = (u16*)nxt((size_t)E_ * E_ * 2);
    u16* wkt   = (u16*)nxt((size_t)E_ * E_ * 2);
    u16* wkres = (u16*)nxt((size_t)E_ * 2048 * 2);
    u16* wvt   = (u16*)nxt((size_t)E_ * E_ * 2);
    u16* wot   = (u16*)nxt((size_t)E_ * E_ * 2);
    float* cost = (float*)nxt((size_t)S_ * 32 * 4);
    float* sint = (float*)nxt((size_t)S_ * 32 * 4);
    u16* qb    = (u16*)nxt((size_t)B_ * H_ * S_ * D_ * 2);
    u16* kb    = (u16*)nxt((size_t)B_ * H_ * S_ * D_ * 2);
    u16* vtb   = (u16*)nxt((size_t)B_ * H_ * S_ * D_ * 2);
    u16* ab    = (u16*)nxt((size_t)BS_ * E_ * 2);
    float* qlast = (float*)nxt((size_t)B_ * E_ * 4);
    float* tscores = (float*)nxt((size_t)B_ * H_ * 128 * 4);

    // merged prep (convert_x + W transposes + rope table + qlast) in one launch
    hipLaunchKernelGGL(prep_kernel, dim3(8512), dim3(256), 0, stream,
                       x, wq, wk, wv, wo, xcat, wqt, wkt, wkres, wvt, wot,
                       cost, sint, qlast);

    // fused projections: RoPE + V-transpose + top-k tile scores in the epilogues
    hipLaunchKernelGGL(proj_gemm_kernel, dim3(768), dim3(256), 0, stream,
                       xcat, wqt, wkt, wkres, wvt, cost, sint, qlast,
                       qb, kb, tscores, vtb);

    // attention
    hipLaunchKernelGGL(flash_kernel, dim3(B_ * H_ * (S_ / 64)), dim3(256), 0, stream,
                       qb, kb, vtb, ab);

    // top-k select (tiny)
    hipLaunchKernelGGL(topk_select_kernel, dim3(B_ * H_), dim3(64), 0, stream,
                       tscores, out + (size_t)BS_ * E_);

    // output projection
    hipLaunchKernelGGL(gemm_bf16_kernel, dim3(256), dim3(256), 0, stream, ab, wot, out,
                       BS_, E_, E_);
}

// Round 11
// 211.535 us; speedup vs baseline: 2.2608x; 1.0483x over previous
//
#include <hip/hip_runtime.h>

#define B_ 2
#define S_ 2048
#define E_ 1024
#define H_ 16
#define D_ 64
#define BS_ (B_*S_)
#define PSTR 76   // flash P-lds stride in u16

typedef unsigned short u16;
typedef __attribute__((ext_vector_type(8))) short short8;
typedef __attribute__((ext_vector_type(4))) float floatx4;
typedef __bf16 bf16x8 __attribute__((ext_vector_type(8)));

__device__ __forceinline__ u16 f2bf(float f) {
    unsigned int u = __builtin_bit_cast(unsigned int, f);
    u += 0x7FFFu + ((u >> 16) & 1u);
    return (u16)(u >> 16);
}
__device__ __forceinline__ float bf2f(u16 h) {
    return __builtin_bit_cast(float, (unsigned int)h << 16);
}
__device__ __forceinline__ floatx4 mfma16(short8 a, short8 b, floatx4 c) {
    return __builtin_amdgcn_mfma_f32_16x16x32_bf16(
        __builtin_bit_cast(bf16x8, a), __builtin_bit_cast(bf16x8, b), c, 0, 0, 0);
}
__device__ __forceinline__ void gload_lds16(const void* g, void* l) {
    __builtin_amdgcn_global_load_lds(
        (const __attribute__((address_space(1))) unsigned int*)g,
        (__attribute__((address_space(3))) unsigned int*)l, 16, 0, 0);
}

// ---------------- merged prep kernel (4 roles by block range) ----------------
__global__ __launch_bounds__(256) void prep_kernel(const float* __restrict__ x,
                                                   const float* __restrict__ wq,
                                                   const float* __restrict__ wk,
                                                   const float* __restrict__ wv,
                                                   const float* __restrict__ wo,
                                                   u16* __restrict__ xcat,
                                                   u16* __restrict__ wqt,
                                                   u16* __restrict__ wkt,
                                                   u16* __restrict__ wkres,
                                                   u16* __restrict__ wvt,
                                                   u16* __restrict__ wot,
                                                   float* __restrict__ cost,
                                                   float* __restrict__ sint,
                                                   float* __restrict__ qlast) {
    __shared__ float t[32][33];
    int bx = blockIdx.x;
    int tid = threadIdx.x;
    if (bx < 4096) {
        int i = bx * 256 + tid;
        int row = i >> 8, c4 = (i & 255) * 4;
        float4 v = ((const float4*)x)[i];
        u16 h0 = f2bf(v.x), h1 = f2bf(v.y), h2 = f2bf(v.z), h3 = f2bf(v.w);
        uint2 o;
        o.x = (unsigned)h0 | ((unsigned)h1 << 16);
        o.y = (unsigned)h2 | ((unsigned)h3 << 16);
        *(uint2*)&xcat[(size_t)row * 2048 + c4] = o;
        u16 l0 = f2bf(v.x - bf2f(h0)), l1 = f2bf(v.y - bf2f(h1));
        u16 l2 = f2bf(v.z - bf2f(h2)), l3 = f2bf(v.w - bf2f(h3));
        uint2 ol;
        ol.x = (unsigned)l0 | ((unsigned)l1 << 16);
        ol.y = (unsigned)l2 | ((unsigned)l3 << 16);
        *(uint2*)&xcat[(size_t)row * 2048 + 1024 + c4] = ol;
    } else if (bx < 8192) {
        int sub = bx - 4096;
        int which = sub >> 10, s2 = sub & 1023;
        const float* W = which == 0 ? wq : which == 1 ? wk : which == 2 ? wv : wo;
        u16* Wt = which == 0 ? wqt : which == 1 ? wkt : which == 2 ? wvt : wot;
        int tk = (s2 >> 5) * 32, tn = (s2 & 31) * 32;
        int tx = tid & 31, ty = tid >> 5;   // 32 x 8
        for (int i = 0; i < 32; i += 8)
            t[ty + i][tx] = W[(size_t)(tk + ty + i) * E_ + tn + tx];
        __syncthreads();
        for (int i = 0; i < 32; i += 8) {
            float v = t[tx][ty + i];
            u16 hi = f2bf(v);
            Wt[(size_t)(tn + ty + i) * E_ + tk + tx] = hi;
            if (which == 1) {
                wkres[(size_t)(tn + ty + i) * 2048 + tk + tx] = f2bf(v - bf2f(hi));
                wkres[(size_t)(tn + ty + i) * 2048 + 1024 + tk + tx] = hi;
            }
        }
    } else if (bx < 8448) {
        int idx = (bx - 8192) * 256 + tid;   // S_*32
        int s = idx >> 5, i = idx & 31;
        float inv = powf(10000.0f, -(float)i / 32.0f);
        float a = (float)s * inv;
        cost[idx] = cosf(a);
        sint[idx] = sinf(a);
    } else {
        float* red = &t[0][0];               // reuse LDS (256 floats)
        int b2 = bx - 8448;
        int b = b2 >> 5, c0 = (b2 & 31) * 32;
        int cl = tid & 31, kc = tid >> 5;
        const float* xr = &x[((size_t)b * S_ + (S_ - 1)) * E_ + kc * 128];
        const float* wp = &wq[(size_t)(kc * 128) * E_ + c0 + cl];
        float acc = 0.f;
#pragma unroll 4
        for (int e = 0; e < 128; ++e) acc = fmaf(xr[e], wp[(size_t)e * E_], acc);
        red[kc * 32 + cl] = acc;
        __syncthreads();
        if (kc == 0) {
            float s = ((red[0 * 32 + cl] + red[1 * 32 + cl]) + (red[2 * 32 + cl] + red[3 * 32 + cl]))
                    + ((red[4 * 32 + cl] + red[5 * 32 + cl]) + (red[6 * 32 + cl] + red[7 * 32 + cl]));
            qlast[(size_t)b * E_ + c0 + cl] = s;
        }
    }
}

// ---------------- GEMM core: 128x128 tile, gload_lds staging, T2 XOR-swizzled LDS ----------------

__device__ __forceinline__ void stage_swz(const u16* __restrict__ src, int row0, int k0,
                                          int stride, u16* lds, int tid) {
    int wv = tid >> 6, ln = tid & 63;
    int swz = (((ln & 7) ^ (ln >> 3)) << 3);   // global col offset (u16) for this lane
    int rr = ln >> 3;
#pragma unroll
    for (int i = 0; i < 4; ++i) {
        int seg = i * 4 + wv;                  // 0..15 ; LDS dest = base + lane*16
        gload_lds16(&src[(size_t)(row0 + seg * 8 + rr) * stride + k0 + swz],
                    (char*)lds + (size_t)seg * 1024);
    }
}

__device__ __forceinline__ void gemm_body(const u16* lA, const u16* lB,
                                          floatx4 (*acc)[4], int lane, int wave) {
    int wm = (wave >> 1) * 64, wn = (wave & 1) * 64;
    int lr = lane & 15, lq = lane >> 4, r7 = lr & 7;
#pragma unroll
    for (int half = 0; half < 2; ++half) {
        int xo = (((half * 4 + lq) ^ r7) << 3);
        short8 afr[4], bfr[4];
#pragma unroll
        for (int mi = 0; mi < 4; ++mi)
            afr[mi] = *(const short8*)&lA[(wm + mi * 16 + lr) * 64 + xo];
#pragma unroll
        for (int ni = 0; ni < 4; ++ni)
            bfr[ni] = *(const short8*)&lB[(wn + ni * 16 + lr) * 64 + xo];
        __builtin_amdgcn_s_setprio(1);
#pragma unroll
        for (int mi = 0; mi < 4; ++mi)
#pragma unroll
            for (int ni = 0; ni < 4; ++ni)
                acc[mi][ni] = mfma16(afr[mi], bfr[ni], acc[mi][ni]);
        __builtin_amdgcn_s_setprio(0);
    }
}

__device__ __forceinline__ void gemm_write(float* __restrict__ C, floatx4 (*acc)[4],
                                           int m0, int n0, int N, int lane, int wave) {
    int wm = (wave >> 1) * 64, wn = (wave & 1) * 64;
    int lr = lane & 15, lq = lane >> 4;
#pragma unroll
    for (int mi = 0; mi < 4; ++mi)
#pragma unroll
        for (int ni = 0; ni < 4; ++ni)
#pragma unroll
            for (int r = 0; r < 4; ++r)
                C[(size_t)(m0 + wm + mi * 16 + lq * 4 + r) * N + n0 + wn + ni * 16 + lr]
                    = acc[mi][ni][r];
}

// RoPE epilogue: rotate adjacent-column lane pairs, write bf16 [bh][s][64].
// K role (qlast != null): also fp32 last-token logits -> per-16-tile maxima -> tscores.
__device__ __forceinline__ void rope_epilogue(floatx4 (*acc)[4], int m0, int n0,
                                              const float* __restrict__ cost,
                                              const float* __restrict__ sint,
                                              const float* __restrict__ qlast,
                                              u16* __restrict__ dstb,
                                              float* __restrict__ tscores,
                                              int lane, int wave) {
    int wm = (wave >> 1) * 64, wn = (wave & 1) * 64;
    int lr = lane & 15, lq = lane >> 4;
    int odd = lr & 1;
    int h = (n0 + wn) >> 6;
    int bq = m0 >> 11;
    int s0 = m0 & 2047;
    float qr[4];
    if (qlast) {
#pragma unroll
        for (int ni = 0; ni < 4; ++ni) {
            int d = ni * 16 + lr;
            int i = d >> 1;
            float qv = qlast[(size_t)bq * E_ + h * 64 + d];
            float qp = __shfl_xor(qv, 1);
            float c = cost[2047 * 32 + i], sn = sint[2047 * 32 + i];
            qr[ni] = odd ? (qp * sn + qv * c) : (qv * c - qp * sn);
        }
    }
    float dotp[4][4];
#pragma unroll
    for (int mi = 0; mi < 4; ++mi)
#pragma unroll
        for (int r = 0; r < 4; ++r) dotp[mi][r] = 0.f;
#pragma unroll
    for (int ni = 0; ni < 4; ++ni) {
        int d = ni * 16 + lr;
        int i = d >> 1;
#pragma unroll
        for (int mi = 0; mi < 4; ++mi) {
#pragma unroll
            for (int r = 0; r < 4; ++r) {
                int row = m0 + wm + mi * 16 + lq * 4 + r;
                int s = row & 2047;
                float own = acc[mi][ni][r];
                float par = __shfl_xor(own, 1);
                float c = cost[s * 32 + i], sn = sint[s * 32 + i];
                float out = odd ? (par * sn + own * c) : (own * c - par * sn);
                dstb[(((size_t)(bq * 16 + h)) * S_ + s) * 64 + d] = f2bf(out);
                if (qlast) dotp[mi][r] += out * qr[ni];
            }
        }
    }
    if (qlast) {
#pragma unroll
        for (int mi = 0; mi < 4; ++mi) {
            float tm = -1e30f;
#pragma unroll
            for (int r = 0; r < 4; ++r) {
                float dv = dotp[mi][r];
                dv += __shfl_xor(dv, 1);
                dv += __shfl_xor(dv, 2);
                dv += __shfl_xor(dv, 4);
                dv += __shfl_xor(dv, 8);
                tm = fmaxf(tm, dv);
            }
            tm = fmaxf(tm, __shfl_xor(tm, 16));
            tm = fmaxf(tm, __shfl_xor(tm, 32));
            if (lane == 0)
                tscores[(size_t)(bq * 16 + h) * 128 + (s0 >> 4) + (wm >> 4) + mi] = tm;
        }
    }
}

// V epilogue: LDS-bounce transpose -> vtb [bh][d][s] bf16 (pad-136 rows)
__device__ __forceinline__ void v_epilogue(floatx4 (*acc)[4], int m0, int n0,
                                           u16* vt, u16* __restrict__ vtb,
                                           int lane, int wave, int tid) {
    int wm = (wave >> 1) * 64, wn = (wave & 1) * 64;
    int lr = lane & 15, lq = lane >> 4;
#pragma unroll
    for (int ni = 0; ni < 4; ++ni) {
        int dcol = wn + ni * 16 + lr;
#pragma unroll
        for (int mi = 0; mi < 4; ++mi)
#pragma unroll
            for (int r = 0; r < 4; ++r)
                vt[dcol * 136 + wm + mi * 16 + lq * 4 + r] = f2bf(acc[mi][ni][r]);
    }
    __syncthreads();
    int dcol = tid >> 1, sh = (tid & 1) * 64;
    int colg = n0 + dcol, h = colg >> 6, d = colg & 63;
    int bq = m0 >> 11, s0 = m0 & 2047;
    size_t base = (((size_t)(bq * 16 + h)) * 64 + d) * S_ + s0 + sh;
#pragma unroll
    for (int c = 0; c < 8; ++c)
        *(uint4*)&vtb[base + c * 8] = *(const uint4*)&vt[dcol * 136 + sh + c * 8];
}

// fused projections (R9 structure: 34.8KB LDS, 4 blocks/CU): 768 blocks, m-strips
// pinned per XCD. role 0: K (two loops, single accumulator) -> rope -> kb + tscores.
// role 1: Q -> rope -> qb. role 2: V -> vtb^T.
__global__ __launch_bounds__(256) void proj_gemm_kernel(const u16* __restrict__ xcat,
                                                        const u16* __restrict__ wqt,
                                                        const u16* __restrict__ wkt,
                                                        const u16* __restrict__ wkres,
                                                        const u16* __restrict__ wvt,
                                                        const float* __restrict__ cost,
                                                        const float* __restrict__ sint,
                                                        const float* __restrict__ qlast,
                                                        u16* __restrict__ qb,
                                                        u16* __restrict__ kb,
                                                        float* __restrict__ tscores,
                                                        u16* __restrict__ vtb) {
    __shared__ __align__(16) u16 lsbuf[17408];   // lA(16KB) + lB(16KB); aliased as vt[128][136]
    u16* lA = lsbuf;
    u16* lB = lsbuf + 8192;
    int bx = blockIdx.x;
    int role = bx >> 8;                          // K first (longest)
    int idx = bx & 255;
    int xcd = idx & 7, loc = idx >> 3;
    int m0 = (xcd * 4 + (loc & 3)) * 128;        // m-strips pinned per XCD (L2-resident A)
    int n0 = (loc >> 2) * 128;
    int tid = threadIdx.x, lane = tid & 63, wave = tid >> 6;

    floatx4 acc[4][4];
#pragma unroll
    for (int i = 0; i < 4; ++i)
#pragma unroll
        for (int j = 0; j < 4; ++j) acc[i][j] = (floatx4){0.f, 0.f, 0.f, 0.f};

    if (role == 0) {
        for (int k0 = 0; k0 < 1024; k0 += 64) {
            stage_swz(xcat, m0, k0, 2048, lA, tid);
            stage_swz(wkt, n0, k0, 1024, lB, tid);
            __syncthreads();
            gemm_body(lA, lB, acc, lane, wave);
            __syncthreads();
        }
        for (int k0 = 0; k0 < 2048; k0 += 64) {
            stage_swz(xcat, m0, k0, 2048, lA, tid);
            stage_swz(wkres, n0, k0, 2048, lB, tid);
            __syncthreads();
            gemm_body(lA, lB, acc, lane, wave);
            __syncthreads();
        }
        rope_epilogue(acc, m0, n0, cost, sint, qlast, kb, tscores, lane, wave);
    } else if (role == 1) {
        for (int k0 = 0; k0 < 1024; k0 += 64) {
            stage_swz(xcat, m0, k0, 2048, lA, tid);
            stage_swz(wqt, n0, k0, 1024, lB, tid);
            __syncthreads();
            gemm_body(lA, lB, acc, lane, wave);
            __syncthreads();
        }
        rope_epilogue(acc, m0, n0, cost, sint, (const float*)nullptr, qb,
                      (float*)nullptr, lane, wave);
    } else {
        for (int k0 = 0; k0 < 1024; k0 += 64) {
            stage_swz(xcat, m0, k0, 2048, lA, tid);
            stage_swz(wvt, n0, k0, 1024, lB, tid);
            __syncthreads();
            gemm_body(lA, lB, acc, lane, wave);
            __syncthreads();
        }
        v_epilogue(acc, m0, n0, lsbuf, vtb, lane, wave, tid);
    }
}

// output projection GEMM, dbuf 2-phase (1 block/CU -> dbuf pays): C = A @ Bt^T
__global__ __launch_bounds__(256) void gemm_bf16_kernel(const u16* __restrict__ A,
                                                        const u16* __restrict__ Bt,
                                                        float* __restrict__ C,
                                                        int M, int N, int Kd) {
    __shared__ __align__(16) u16 lds4[4 * 8192];
    u16* T0 = lds4;
    u16* T1 = lds4 + 8192;
    u16* T2 = lds4 + 16384;
    u16* T3 = lds4 + 24576;
    int nwg = (M / 128) * (N / 128);
    int bx = blockIdx.x;
    int q = nwg >> 3, rr = nwg & 7, xcd = bx & 7, pos = bx >> 3;
    int lbx = (xcd < rr ? xcd * (q + 1) : rr * (q + 1) + (xcd - rr) * q) + pos;
    int nbn = N / 128;
    int m0 = (lbx / nbn) * 128, n0 = (lbx % nbn) * 128;
    int tid = threadIdx.x, lane = tid & 63, wave = tid >> 6;

    floatx4 acc[4][4];
#pragma unroll
    for (int i = 0; i < 4; ++i)
#pragma unroll
        for (int j = 0; j < 4; ++j) acc[i][j] = (floatx4){0.f, 0.f, 0.f, 0.f};

    int nsteps = Kd / 64;
    stage_swz(A, m0, 0, Kd, T0, tid);
    stage_swz(Bt, n0, 0, Kd, T2, tid);
    asm volatile("s_waitcnt vmcnt(0)" ::: "memory");
    __syncthreads();
    for (int step = 0; step < nsteps; ++step) {
        int buf = step & 1;
        u16* Ac = buf ? T1 : T0;
        u16* Bc = buf ? T3 : T2;
        if (step + 1 < nsteps) {
            stage_swz(A, m0, (step + 1) * 64, Kd, buf ? T0 : T1, tid);
            stage_swz(Bt, n0, (step + 1) * 64, Kd, buf ? T2 : T3, tid);
        }
        gemm_body(Ac, Bc, acc, lane, wave);
        asm volatile("s_waitcnt vmcnt(0)" ::: "memory");
        __syncthreads();
    }
    gemm_write(C, acc, m0, n0, N, lane, wave);
}

// ---------------- flash attention: LDS-DMA staged K/V, fragment-major segs ----------------
__device__ __forceinline__ void stage_kv(const u16* __restrict__ K, const u16* __restrict__ V,
                                         int n0, u16* kbuf, u16* vbuf, int wave, int lane) {
    int lr = lane & 15, lq = lane >> 4;
    if (wave < 2) {
#pragma unroll
        for (int i = 0; i < 4; ++i) {
            int sk = wave * 4 + i;            // seg = kt*2 + kh
            int kt = sk >> 1, kh = (sk & 1) * 32;
            gload_lds16(&K[(size_t)(n0 + kt * 16 + lr) * D_ + kh + lq * 8],
                        kbuf + sk * 512);
        }
    } else {
#pragma unroll
        for (int i = 0; i < 4; ++i) {
            int sv = (wave - 2) * 4 + i;      // seg = c*4 + o
            int c = sv >> 2, o = sv & 3;
            gload_lds16(&V[(size_t)(o * 16 + lr) * S_ + n0 + c * 32 + lq * 8],
                        vbuf + sv * 512);
        }
    }
}

__global__ __launch_bounds__(256) void flash_kernel(const u16* __restrict__ qb,
                                                    const u16* __restrict__ kb,
                                                    const u16* __restrict__ vtb,
                                                    u16* __restrict__ ab) {
    __shared__ __align__(16) u16 kls[2][8 * 512];
    __shared__ __align__(16) u16 vls[2][8 * 512];
    __shared__ __align__(16) u16 ldsP[4][16 * PSTR];
    int tid = threadIdx.x;
    int lane = tid & 63, wave = tid >> 6;
    int bx = blockIdx.x;
    int xcd = bx & 7, ii = bx >> 3;
    int hid = xcd + 8 * (ii & 3);   // 4 heads per XCD -> K/V L2-resident
    int qc = 31 - (ii >> 2);        // longest q-chunks dispatch first
    int qt0 = qc * 64 + wave * 16;
    const u16* Q = qb + (size_t)hid * S_ * D_;
    const u16* K = kb + (size_t)hid * S_ * D_;
    const u16* V = vtb + (size_t)hid * D_ * S_;
    u16* lp = &ldsP[wave][0];
    int lr = lane & 15, lq = lane >> 4, lk = lq * 8;

    short8 qfr0 = *(const short8*)&Q[(size_t)(qt0 + lr) * D_ + lk];
    short8 qfr1 = *(const short8*)&Q[(size_t)(qt0 + lr) * D_ + 32 + lk];

    floatx4 o0 = {0,0,0,0}, o1 = {0,0,0,0}, o2 = {0,0,0,0}, o3 = {0,0,0,0};
    float m = -1e30f, l = 0.f;

    stage_kv(K, V, 0, kls[0], vls[0], wave, lane);
    asm volatile("s_waitcnt vmcnt(0)" ::: "memory");
    __syncthreads();

    for (int it = 0; it <= qc; ++it) {
        int n0 = it * 64;
        int buf = it & 1;
        const u16* kbuf = kls[buf];
        const u16* vbuf = vls[buf];
        if (it < qc)
            stage_kv(K, V, n0 + 64, kls[buf ^ 1], vls[buf ^ 1], wave, lane);

        short8 ka0[4], ka1[4];
#pragma unroll
        for (int kt = 0; kt < 4; ++kt) {
            ka0[kt] = *(const short8*)&kbuf[(kt * 2 + 0) * 512 + lane * 8];
            ka1[kt] = *(const short8*)&kbuf[(kt * 2 + 1) * 512 + lane * 8];
        }
        floatx4 st[4];
#pragma unroll
        for (int kt = 0; kt < 4; ++kt) st[kt] = (floatx4){0.f, 0.f, 0.f, 0.f};
        __builtin_amdgcn_s_setprio(1);
#pragma unroll
        for (int kt = 0; kt < 4; ++kt) {
            st[kt] = mfma16(ka0[kt], qfr0, st[kt]);
            st[kt] = mfma16(ka1[kt], qfr1, st[kt]);
        }
        __builtin_amdgcn_s_setprio(0);

        const float SC = 0.18033688011112042f;   // 0.125 * log2(e)
        int rem = qt0 + 16 - n0;
        float sv[4][4];
        float bmax = -1e30f;
        if (rem >= 80) {
#pragma unroll
            for (int kt = 0; kt < 4; ++kt)
#pragma unroll
                for (int r = 0; r < 4; ++r) {
                    float s = st[kt][r] * SC;
                    sv[kt][r] = s;
                    bmax = fmaxf(bmax, s);
                }
        } else {
#pragma unroll
            for (int kt = 0; kt < 4; ++kt)
#pragma unroll
                for (int r = 0; r < 4; ++r) {
                    int k = n0 + kt * 16 + lq * 4 + r;
                    float s = (k <= qt0 + lr) ? st[kt][r] * SC : -1e30f;
                    sv[kt][r] = s;
                    bmax = fmaxf(bmax, s);
                }
        }
        bmax = fmaxf(bmax, __shfl_xor(bmax, 16));
        bmax = fmaxf(bmax, __shfl_xor(bmax, 32));
        if (!__all(bmax <= m + 8.0f)) {
            float mn = fmaxf(m, bmax);
            float alpha = __builtin_amdgcn_exp2f(m - mn);
            m = mn;
            l *= alpha;
            float af[4];
#pragma unroll
            for (int r = 0; r < 4; ++r) af[r] = __shfl(alpha, lq * 4 + r);
#pragma unroll
            for (int r = 0; r < 4; ++r) {
                o0[r] *= af[r]; o1[r] *= af[r]; o2[r] *= af[r]; o3[r] *= af[r];
            }
        }
        float ps = 0.f;
#pragma unroll
        for (int kt = 0; kt < 4; ++kt) {
            float p0 = __builtin_amdgcn_exp2f(sv[kt][0] - m);
            float p1 = __builtin_amdgcn_exp2f(sv[kt][1] - m);
            float p2 = __builtin_amdgcn_exp2f(sv[kt][2] - m);
            float p3 = __builtin_amdgcn_exp2f(sv[kt][3] - m);
            ps += (p0 + p1) + (p2 + p3);
            unsigned wlo, whi;
            asm("v_cvt_pk_bf16_f32 %0, %1, %2" : "=v"(wlo) : "v"(p0), "v"(p1));
            asm("v_cvt_pk_bf16_f32 %0, %1, %2" : "=v"(whi) : "v"(p2), "v"(p3));
            *(uint2*)&lp[lr * PSTR + kt * 16 + lq * 4] = (uint2){wlo, whi};
        }
        ps += __shfl_xor(ps, 16);
        ps += __shfl_xor(ps, 32);
        l += ps;

        short8 vv[2][4];
#pragma unroll
        for (int c = 0; c < 2; ++c)
#pragma unroll
            for (int o = 0; o < 4; ++o)
                vv[c][o] = *(const short8*)&vbuf[(c * 4 + o) * 512 + lane * 8];
        asm volatile("s_waitcnt lgkmcnt(0)" ::: "memory");
        __builtin_amdgcn_s_setprio(1);
#pragma unroll
        for (int c = 0; c < 2; ++c) {
            uint2 plo = *(const uint2*)&lp[lr * PSTR + c * 32 + lk];
            uint2 phi = *(const uint2*)&lp[lr * PSTR + c * 32 + lk + 4];
            short8 pfr = __builtin_bit_cast(short8, (uint4){plo.x, plo.y, phi.x, phi.y});
            o0 = mfma16(pfr, vv[c][0], o0);
            o1 = mfma16(pfr, vv[c][1], o1);
            o2 = mfma16(pfr, vv[c][2], o2);
            o3 = mfma16(pfr, vv[c][3], o3);
        }
        __builtin_amdgcn_s_setprio(0);

        if (it < qc) {
            asm volatile("s_waitcnt vmcnt(0)" ::: "memory");
            __syncthreads();
        }
    }
    float li[4];
#pragma unroll
    for (int r = 0; r < 4; ++r) li[r] = 1.0f / __shfl(l, lq * 4 + r);
    int b = hid >> 4, h = hid & 15;
    size_t orow_base = ((size_t)b * S_ + qt0 + lq * 4) * E_ + h * D_;
#pragma unroll
    for (int r = 0; r < 4; ++r) {
        size_t rb = orow_base + (size_t)r * E_;
        ab[rb + 0  + lr] = f2bf(o0[r] * li[r]);
        ab[rb + 16 + lr] = f2bf(o1[r] * li[r]);
        ab[rb + 32 + lr] = f2bf(o2[r] * li[r]);
        ab[rb + 48 + lr] = f2bf(o3[r] * li[r]);
    }
}

// ---------------- top-8 select from precomputed tile scores ----------------
__global__ __launch_bounds__(64) void topk_select_kernel(const float* __restrict__ tscores,
                                                         float* __restrict__ oidx) {
    int bh = blockIdx.x, tid = threadIdx.x;
    float v0 = tscores[bh * 128 + tid], v1 = tscores[bh * 128 + 64 + tid];
    float va, vb; int ia, ib;
    if (v1 > v0) { va = v1; ia = tid + 64; vb = v0; ib = tid; }
    else         { va = v0; ia = tid;      vb = v1; ib = tid + 64; }
    float cv = va; int ci = ia; int used = 0;
    for (int t = 0; t < 8; ++t) {
        float bv = cv; int bi = ci;
#pragma unroll
        for (int mk = 1; mk < 64; mk <<= 1) {
            float ov = __shfl_xor(bv, mk);
            int oi = __shfl_xor(bi, mk);
            if (ov > bv || (ov == bv && oi < bi)) { bv = ov; bi = oi; }
        }
        if (tid == 0) oidx[bh * 8 + t] = (float)bi;
        if (ci == bi) {
            if (used == 0) { cv = vb; ci = ib; used = 1; }
            else           { cv = -3e30f; ci = 1 << 20; }
        }
    }
}

// ---------------- launch ----------------
extern "C" void kernel_launch(void* const* d_in, const int* in_sizes, int n_in,
                              void* d_out, int out_size, void* d_ws, size_t ws_size,
                              hipStream_t stream) {
    (void)in_sizes; (void)n_in; (void)out_size; (void)ws_size;
    const float* x  = (const float*)d_in[0];
    const float* wq = (const float*)d_in[1];
    const float* wk = (const float*)d_in[2];
    const float* wv = (const float*)d_in[3];
    const float* wo = (const float*)d_in[4];
    float* out = (float*)d_out;

    char* wsp = (char*)d_ws;
    size_t off = 0;
    auto nxt = [&](size_t bytes) {
        char* p = wsp + off;
        off = (off + bytes + 255) & ~(size_t)255;
        return p;
    };
    u16* xcat  = (u16*)nxt((size_t)BS_ * 2048 * 2);
    u16* wqt   = (u16*)nxt((size_t)E_ * E_ * 2);
    u16* wkt   = (u16*)nxt((size_t)E_ * E_ * 2);
    u16* wkres = (u16*)nxt((size_t)E_ * 2048 * 2);
    u16* wvt   = (u16*)nxt((size_t)E_ * E_ * 2);
    u16* wot   = (u16*)nxt((size_t)E_ * E_ * 2);
    float* cost = (float*)nxt((size_t)S_ * 32 * 4);
    float* sint = (float*)nxt((size_t)S_ * 32 * 4);
    u16* qb    = (u16*)nxt((size_t)B_ * H_ * S_ * D_ * 2);
    u16* kb    = (u16*)nxt((size_t)B_ * H_ * S_ * D_ * 2);
    u16* vtb   = (u16*)nxt((size_t)B_ * H_ * S_ * D_ * 2);
    u16* ab    = (u16*)nxt((size_t)BS_ * E_ * 2);
    float* qlast = (float*)nxt((size_t)B_ * E_ * 4);
    float* tscores = (float*)nxt((size_t)B_ * H_ * 128 * 4);

    // merged prep (convert_x + W transposes + rope table + qlast) in one launch
    hipLaunchKernelGGL(prep_kernel, dim3(8512), dim3(256), 0, stream,
                       x, wq, wk, wv, wo, xcat, wqt, wkt, wkres, wvt, wot,
                       cost, sint, qlast);

    // fused projections: RoPE + V-transpose + top-k tile scores in the epilogues
    hipLaunchKernelGGL(proj_gemm_kernel, dim3(768), dim3(256), 0, stream,
                       xcat, wqt, wkt, wkres, wvt, cost, sint, qlast,
                       qb, kb, tscores, vtb);

    // attention
    hipLaunchKernelGGL(flash_kernel, dim3(B_ * H_ * (S_ / 64)), dim3(256), 0, stream,
                       qb, kb, vtb, ab);

    // top-k select (tiny)
    hipLaunchKernelGGL(topk_select_kernel, dim3(B_ * H_), dim3(64), 0, stream,
                       tscores, out + (size_t)BS_ * E_);

    // output projection
    hipLaunchKernelGGL(gemm_bf16_kernel, dim3(256), dim3(256), 0, stream, ab, wot, out,
                       BS_, E_, E_);
}